// Round 1
// baseline (4141.127 us; speedup 1.0000x reference)
//
#include <hip/hip_runtime.h>

// PtrNet greedy decode, B=16, N=1000, H=128, M=2, 16 steps.
// Phase 1: proj_kernel — 13x [16000x128]@[128x128] f32 GEMM into ws.
// Phase 2: decode_kernel — persistent cooperative kernel, 16 groups (one per
//          batch) x 16 blocks, group-local atomic barriers, online softmax
//          with fixed max=10 (scores are clip-tanh-bounded).

#define Bb 16
#define Nn 1000
#define Hh 128
#define Ss 16
#define TPT (Nn * Bb * Hh)   // elems per projection tensor slot: 2,048,000

// partials slot: [par][g][c][m][132]; [0..2] scalars, [4+h] vector payload
#define PPART(par, g, c, m) \
  ((((size_t)(par)*16 + (size_t)(g))*16 + (size_t)(c))*2 + (size_t)(m))*132

__device__ __forceinline__ float red5(float a) {
#pragma unroll
  for (int m = 1; m <= 16; m <<= 1) a += __shfl_xor(a, m, 64);
  return a;
}
__device__ __forceinline__ void red5_2(float& a, float& b) {
#pragma unroll
  for (int m = 1; m <= 16; m <<= 1) {
    a += __shfl_xor(a, m, 64);
    b += __shfl_xor(b, m, 64);
  }
}

__device__ __forceinline__ void group_barrier(int* cnt, int tid) {
  __syncthreads();
  if (tid == 0) {
    __threadfence();  // flush this XCD's L2 so partials are agent-visible
    __hip_atomic_fetch_add(cnt, 1, __ATOMIC_RELEASE, __HIP_MEMORY_SCOPE_AGENT);
    while (__hip_atomic_load(cnt, __ATOMIC_RELAXED, __HIP_MEMORY_SCOPE_AGENT) < 16)
      __builtin_amdgcn_s_sleep(4);
    __threadfence();  // acquire: invalidate L1/L2 before reading partials
  }
  __syncthreads();
}

// ---------------------------------------------------------------- projections
__global__ __launch_bounds__(256) void ptr1_proj_kernel(
    const float* __restrict__ enc,
    const float* __restrict__ Wref1, const float* __restrict__ Vec1,
    const float* __restrict__ Wref3, const float* __restrict__ Vec3,
    const float* __restrict__ Wref4, const float* __restrict__ Vec4,
    const float* __restrict__ Wref2,
    float* __restrict__ outp) {
  __shared__ float At[128][64];  // A transposed [k][row]
  __shared__ float Bs[128][64];  // B [k][col-half]
  const int rt = blockIdx.x;     // 0..249 row tiles of 64
  const int wy = blockIdx.y;     // 0..25
  const int mat = wy >> 1;       // 0..12 output slot
  const int ch = wy & 1;         // column half
  const int tid = threadIdx.x;

  const float* W;
  switch (mat >> 1) {
    case 0: W = Wref1; break;
    case 1: W = Vec1;  break;
    case 2: W = Wref3; break;
    case 3: W = Vec3;  break;
    case 4: W = Wref4; break;
    case 5: W = Vec4;  break;
    default: W = Wref2; break;
  }
  if (mat < 12) W += (size_t)(mat & 1) * (128 * 128);

  const float* asrc = enc + (size_t)rt * 64 * 128;
  for (int f = tid; f < 64 * 32; f += 256) {
    const int r = f >> 5, k4 = (f & 31) << 2;
    const float4 v = *(const float4*)(asrc + (size_t)r * 128 + k4);
    At[k4 + 0][r] = v.x; At[k4 + 1][r] = v.y;
    At[k4 + 2][r] = v.z; At[k4 + 3][r] = v.w;
  }
  for (int f = tid; f < 128 * 16; f += 256) {
    const int k = f >> 4, c4 = (f & 15) << 2;
    *(float4*)&Bs[k][c4] = *(const float4*)(W + (size_t)k * 128 + ch * 64 + c4);
  }
  __syncthreads();

  const int tx = tid & 15, ty = tid >> 4;
  float acc[4][4] = {{0.f}};
  for (int k = 0; k < 128; ++k) {
    const float4 a = *(const float4*)&At[k][ty * 4];
    const float4 b = *(const float4*)&Bs[k][tx * 4];
    acc[0][0] += a.x * b.x; acc[0][1] += a.x * b.y; acc[0][2] += a.x * b.z; acc[0][3] += a.x * b.w;
    acc[1][0] += a.y * b.x; acc[1][1] += a.y * b.y; acc[1][2] += a.y * b.z; acc[1][3] += a.y * b.w;
    acc[2][0] += a.z * b.x; acc[2][1] += a.z * b.y; acc[2][2] += a.z * b.z; acc[2][3] += a.z * b.w;
    acc[3][0] += a.w * b.x; acc[3][1] += a.w * b.y; acc[3][2] += a.w * b.z; acc[3][3] += a.w * b.w;
  }
  float* dst = outp + (size_t)mat * TPT + ((size_t)rt * 64 + ty * 4) * 128 + ch * 64 + tx * 4;
  for (int i = 0; i < 4; ++i) {
    float4 v; v.x = acc[i][0]; v.y = acc[i][1]; v.z = acc[i][2]; v.w = acc[i][3];
    *(float4*)(dst + (size_t)i * 128) = v;
  }
}

// ------------------------------------------------------------------- decode
__global__ __launch_bounds__(256, 1) void ptr1_decode_kernel(
    const float* __restrict__ enc, const float* __restrict__ mask0,
    const float* __restrict__ Wq1, const float* __restrict__ Wq3,
    const float* __restrict__ Wq4, const float* __restrict__ Wmh,
    const float* __restrict__ Wq2, const float* __restrict__ Vec2,
    const float* __restrict__ dec_inp, const float* __restrict__ proj,
    float* __restrict__ partials, int* __restrict__ counters,
    float* __restrict__ out) {
  const int g = blockIdx.x >> 4;   // batch / group
  const int c = blockIdx.x & 15;   // block within group
  const int tid = threadIdx.x;
  const int wv = tid >> 6;         // wave 0..3
  const int lane = tid & 63;
  const int half = lane >> 5;      // 32-lane half handles one row
  const int hl = lane & 31;
  const int h0 = hl << 2;          // 4 h-elems per lane
  const int start = c * 63;
  const int cnt = min(63, Nn - start);

  __shared__ __align__(16) float hmean[128];
  __shared__ __align__(16) float qcur[256];
  __shared__ __align__(16) float qm[2][128];
  __shared__ __align__(16) float gf[256];
  __shared__ __align__(16) float vecl[128];
  __shared__ __align__(16) float wpart[4][2][132];
  __shared__ float maskl[64];
  __shared__ float ulocal[64];
  __shared__ int sel_sh;
  __shared__ float logZ_sh;

  if (tid < 128) vecl[tid] = Vec2[tid];
  for (int j = tid; j < cnt; j += 256) maskl[j] = mask0[(size_t)g * Nn + start + j];

  // ---- phase 0: h_mean = mean_n enc[g,n,:] ----
  {
    float4 a = {0.f, 0.f, 0.f, 0.f};
    const float* eb = enc + ((size_t)g * Nn + start) * Hh + h0;
    for (int j = wv * 2 + half; j < cnt; j += 8) {
      const float4 e4 = *(const float4*)(eb + (size_t)j * Hh);
      a.x += e4.x; a.y += e4.y; a.z += e4.z; a.w += e4.w;
    }
    a.x += __shfl_xor(a.x, 32, 64); a.y += __shfl_xor(a.y, 32, 64);
    a.z += __shfl_xor(a.z, 32, 64); a.w += __shfl_xor(a.w, 32, 64);
    if (half == 0) *(float4*)&wpart[wv][0][4 + h0] = a;
    __syncthreads();
    if (tid < 128) {
      float s = wpart[0][0][4 + tid] + wpart[1][0][4 + tid] +
                wpart[2][0][4 + tid] + wpart[3][0][4 + tid];
      partials[PPART(0, g, c, 0) + 4 + tid] = s;
    }
    group_barrier(&counters[0 * 16 + g], tid);
    if (tid < 128) {
      float s = 0.f;
      for (int cc = 0; cc < 16; ++cc) s += partials[PPART(0, g, cc, 0) + 4 + tid];
      hmean[tid] = s * (1.0f / (float)Nn);
    }
    __syncthreads();
  }

  int sel = -1;
  int p = 1;
  for (int step = 0; step < Ss; ++step) {
    // q0 = concat(h_mean, prev)
    if (tid < 128) {
      qcur[tid] = hmean[tid];
    } else {
      const int h = tid - 128;
      qcur[tid] = (step == 0) ? dec_inp[h] : enc[((size_t)g * Nn + sel) * Hh + h];
    }
    __syncthreads();

    for (int gl = 0; gl < 3; ++gl) {
      const float* Wq = (gl == 0) ? Wq1 : ((gl == 1) ? Wq3 : Wq4);
      const int Din = (gl == 0) ? 256 : 128;
      {  // q[m][h] = sum_i qcur[i] * Wq[m,i,h]   (redundant per block, tiny)
        const int m = tid >> 7, h = tid & 127;
        float acc = 0.f;
        const float* wp = Wq + (size_t)m * Din * 128 + h;
        for (int i = 0; i < Din; ++i) acc += qcur[i] * wp[(size_t)i * 128];
        qm[m][h] = acc;
      }
      __syncthreads();

      const float4 qa = *(const float4*)&qm[0][h0];
      const float4 qb = *(const float4*)&qm[1][h0];
      const size_t rowb = ((size_t)g * Nn + start) * Hh + h0;
      const float* r0p = proj + (size_t)(4 * gl + 0) * TPT + rowb;
      const float* r1p = proj + (size_t)(4 * gl + 1) * TPT + rowb;
      const float* v0p = proj + (size_t)(4 * gl + 2) * TPT + rowb;
      const float* v1p = proj + (size_t)(4 * gl + 3) * TPT + rowb;
      float S0 = 0.f, S1 = 0.f;
      float4 g0 = {0.f, 0.f, 0.f, 0.f}, g1 = {0.f, 0.f, 0.f, 0.f};
      for (int j = wv * 2 + half; j < cnt; j += 8) {
        const size_t off = (size_t)j * Hh;
        const float4 r0 = *(const float4*)(r0p + off);
        const float4 v0 = *(const float4*)(v0p + off);
        const float4 r1 = *(const float4*)(r1p + off);
        const float4 v1 = *(const float4*)(v1p + off);
        const float ml = maskl[j];
        float s0 = tanhf(qa.x + r0.x) * v0.x + tanhf(qa.y + r0.y) * v0.y +
                   tanhf(qa.z + r0.z) * v0.z + tanhf(qa.w + r0.w) * v0.w;
        float s1 = tanhf(qb.x + r1.x) * v1.x + tanhf(qb.y + r1.y) * v1.y +
                   tanhf(qb.z + r1.z) * v1.z + tanhf(qb.w + r1.w) * v1.w;
        red5_2(s0, s1);  // 32-lane sums (one row per half-wave)
        s0 = 10.f * tanhf(s0) - 1e8f * ml;
        s1 = 10.f * tanhf(s1) - 1e8f * ml;
        const float e0 = expf(s0 - 10.f);  // fixed max: scores are in [-10,10]
        const float e1 = expf(s1 - 10.f);
        S0 += e0; S1 += e1;
        g0.x += e0 * r0.x; g0.y += e0 * r0.y; g0.z += e0 * r0.z; g0.w += e0 * r0.w;
        g1.x += e1 * r1.x; g1.y += e1 * r1.y; g1.z += e1 * r1.z; g1.w += e1 * r1.w;
      }
      // combine halves (same h, different rows)
      S0 += __shfl_xor(S0, 32, 64); S1 += __shfl_xor(S1, 32, 64);
      g0.x += __shfl_xor(g0.x, 32, 64); g0.y += __shfl_xor(g0.y, 32, 64);
      g0.z += __shfl_xor(g0.z, 32, 64); g0.w += __shfl_xor(g0.w, 32, 64);
      g1.x += __shfl_xor(g1.x, 32, 64); g1.y += __shfl_xor(g1.y, 32, 64);
      g1.z += __shfl_xor(g1.z, 32, 64); g1.w += __shfl_xor(g1.w, 32, 64);
      if (half == 0) {
        *(float4*)&wpart[wv][0][4 + h0] = g0;
        *(float4*)&wpart[wv][1][4 + h0] = g1;
        if (hl == 0) { wpart[wv][0][0] = S0; wpart[wv][1][0] = S1; }
      }
      __syncthreads();
      const int par = p & 1;
      {  // block combine -> global partial
        const int m = tid >> 7, h = tid & 127;
        float gs = wpart[0][m][4 + h] + wpart[1][m][4 + h] +
                   wpart[2][m][4 + h] + wpart[3][m][4 + h];
        float* gp = partials + PPART(par, g, c, m);
        gp[4 + h] = gs;
        if (h == 0)
          gp[0] = wpart[0][m][0] + wpart[1][m][0] + wpart[2][m][0] + wpart[3][m][0];
      }
      group_barrier(&counters[p * 16 + g], tid);
      {  // group combine (redundant per block, deterministic)
        const int m = tid >> 7, h = tid & 127;
        float Sx = 0.f, gx = 0.f;
        for (int cc = 0; cc < 16; ++cc) {
          const float* gp = partials + PPART(par, g, cc, m);
          Sx += gp[0];
          gx += gp[4 + h];
        }
        gf[m * 128 + h] = gx / Sx;  // softmax-weighted glimpse
      }
      p++;
      __syncthreads();
      if (tid < 128) {  // merge heads: qnext = g_flat @ Wmh
        float acc = 0.f;
        const float* wp = Wmh + tid;
        for (int i = 0; i < 256; ++i) acc += gf[i] * wp[(size_t)i * 128];
        qcur[tid] = acc;
      }
      __syncthreads();
    }

    // ---- pointer ----
    if (tid < 128) {
      float acc = 0.f;
      const float* wp = Wq2 + tid;
      for (int i = 0; i < 128; ++i) acc += qcur[i] * wp[(size_t)i * 128];
      qm[0][tid] = acc;
    }
    __syncthreads();
    {
      const float4 q2 = *(const float4*)&qm[0][h0];
      const float4 vz = *(const float4*)&vecl[h0];
      const float* r2p = proj + (size_t)12 * TPT + ((size_t)g * Nn + start) * Hh + h0;
      float Sv = 0.f, um = -3.0e38f; int ui = 0x7fffffff;
      for (int j = wv * 2 + half; j < cnt; j += 8) {
        const float4 rr = *(const float4*)(r2p + (size_t)j * Hh);
        float up = tanhf(q2.x + rr.x) * vz.x + tanhf(q2.y + rr.y) * vz.y +
                   tanhf(q2.z + rr.z) * vz.z + tanhf(q2.w + rr.w) * vz.w;
        up = red5(up);
        const float u = 10.f * tanhf(up) - 1e8f * maskl[j];
        if (hl == 0) ulocal[j] = u;
        Sv += expf(u - 10.f);
        if (u > um) { um = u; ui = start + j; }  // '>' keeps first index
      }
      Sv += __shfl_xor(Sv, 32, 64);
      const float um2 = __shfl_xor(um, 32, 64);
      const int ui2 = __shfl_xor(ui, 32, 64);
      if (um2 > um || (um2 == um && ui2 < ui)) { um = um2; ui = ui2; }
      if (lane == 0) {
        wpart[wv][0][0] = Sv; wpart[wv][0][1] = um;
        wpart[wv][0][2] = __int_as_float(ui);
      }
    }
    __syncthreads();
    const int par = p & 1;
    if (tid == 0) {
      float St = 0.f, bm = -3.0e38f; int bi = 0x7fffffff;
      for (int ww = 0; ww < 4; ++ww) {
        St += wpart[ww][0][0];
        const float m2 = wpart[ww][0][1];
        const int i2 = __float_as_int(wpart[ww][0][2]);
        if (m2 > bm || (m2 == bm && i2 < bi)) { bm = m2; bi = i2; }
      }
      float* gp = partials + PPART(par, g, c, 0);
      gp[0] = St; gp[1] = bm; gp[2] = __int_as_float(bi);
    }
    group_barrier(&counters[p * 16 + g], tid);
    if (tid == 0) {
      float St = 0.f, bm = -3.0e38f; int bi = 0x7fffffff;
      for (int cc = 0; cc < 16; ++cc) {
        const float* gp = partials + PPART(par, g, cc, 0);
        St += gp[0];
        const float m2 = gp[1];
        const int i2 = __float_as_int(gp[2]);
        if (m2 > bm || (m2 == bm && i2 < bi)) { bm = m2; bi = i2; }
      }
      sel_sh = bi;
      logZ_sh = 10.f + logf(St);  // logsumexp with fixed shift 10
    }
    p++;
    __syncthreads();
    sel = sel_sh;
    const float lz = logZ_sh;
    for (int j = tid; j < cnt; j += 256)
      out[(size_t)step * (Bb * Nn) + (size_t)g * Nn + start + j] = ulocal[j] - lz;
    if (c == 0 && tid == 0)
      out[(size_t)Ss * Bb * Nn + (size_t)step * Bb + g] = (float)sel;
    if (tid == 0 && sel >= start && sel < start + cnt) maskl[sel - start] = 1.0f;
    __syncthreads();
  }
}

// -------------------------------------------------------------------- launch
extern "C" void kernel_launch(void* const* d_in, const int* in_sizes, int n_in,
                              void* d_out, int out_size, void* d_ws, size_t ws_size,
                              hipStream_t stream) {
  const float* enc     = (const float*)d_in[0];
  const float* mask0   = (const float*)d_in[1];
  const float* Wq1     = (const float*)d_in[2];
  const float* Wref1   = (const float*)d_in[3];
  const float* Vec1    = (const float*)d_in[4];
  const float* Wq3     = (const float*)d_in[5];
  const float* Wref3   = (const float*)d_in[6];
  const float* Vec3    = (const float*)d_in[7];
  const float* Wq4     = (const float*)d_in[8];
  const float* Wref4   = (const float*)d_in[9];
  const float* Vec4    = (const float*)d_in[10];
  const float* Wmh     = (const float*)d_in[11];
  const float* Wq2     = (const float*)d_in[12];
  const float* Wref2   = (const float*)d_in[13];
  const float* Vec2    = (const float*)d_in[14];
  const float* dec_inp = (const float*)d_in[15];
  float* out = (float*)d_out;

  char* ws = (char*)d_ws;
  int* counters   = (int*)ws;                       // 65*16 ints, < 8 KB
  float* partials = (float*)(ws + 8192);            // 540,672 B
  float* proj     = (float*)(ws + 548864);          // 13 * 2,048,000 f32

  hipMemsetAsync(counters, 0, 8192, stream);

  dim3 pg(250, 26);
  ptr1_proj_kernel<<<pg, 256, 0, stream>>>(enc, Wref1, Vec1, Wref3, Vec3,
                                           Wref4, Vec4, Wref2, proj);

  void* args[] = {(void*)&enc,  (void*)&mask0, (void*)&Wq1, (void*)&Wq3,
                  (void*)&Wq4,  (void*)&Wmh,   (void*)&Wq2, (void*)&Vec2,
                  (void*)&dec_inp, (void*)&proj, (void*)&partials,
                  (void*)&counters, (void*)&out};
  hipLaunchCooperativeKernel((const void*)ptr1_decode_kernel, dim3(256),
                             dim3(256), args, 0, stream);
}

// Round 2
// 1940.231 us; speedup vs baseline: 2.1343x; 2.1343x over previous
//
#include <hip/hip_runtime.h>

// PtrNet greedy decode, B=16, N=1000, H=128, M=2, 16 steps.
// Phase 1: proj_kernel — 13x [16000x128]@[128x128] f32 GEMM into ws.
// Phase 2: decode_kernel — persistent cooperative kernel, 16 groups (one per
//          batch) x 16 blocks x 1024 threads (16 waves/CU for latency hiding),
//          group-local atomic barriers, online softmax with fixed max=10.

#define Bb 16
#define Nn 1000
#define Hh 128
#define Ss 16
#define TPB 1024
#define NW 16                 // waves per block
#define TPT (Nn * Bb * Hh)    // elems per projection tensor slot: 2,048,000

// partials slot: [par][g][c][m][132]; [0..2] scalars, [4+h] vector payload
#define PPART(par, g, c, m) \
  ((((size_t)(par)*16 + (size_t)(g))*16 + (size_t)(c))*2 + (size_t)(m))*132

__device__ __forceinline__ float red5(float a) {
#pragma unroll
  for (int m = 1; m <= 16; m <<= 1) a += __shfl_xor(a, m, 64);
  return a;
}
__device__ __forceinline__ void red5_2(float& a, float& b) {
#pragma unroll
  for (int m = 1; m <= 16; m <<= 1) {
    a += __shfl_xor(a, m, 64);
    b += __shfl_xor(b, m, 64);
  }
}

__device__ __forceinline__ void group_barrier(int* cnt, int tid) {
  __syncthreads();
  if (tid == 0) {
    __threadfence();  // release: make partials agent-visible
    __hip_atomic_fetch_add(cnt, 1, __ATOMIC_RELEASE, __HIP_MEMORY_SCOPE_AGENT);
    while (__hip_atomic_load(cnt, __ATOMIC_RELAXED, __HIP_MEMORY_SCOPE_AGENT) < 16)
      __builtin_amdgcn_s_sleep(4);
    __threadfence();  // acquire: invalidate caches before reading partials
  }
  __syncthreads();
}

// ---------------------------------------------------------------- projections
__global__ __launch_bounds__(256) void ptr1_proj_kernel(
    const float* __restrict__ enc,
    const float* __restrict__ Wref1, const float* __restrict__ Vec1,
    const float* __restrict__ Wref3, const float* __restrict__ Vec3,
    const float* __restrict__ Wref4, const float* __restrict__ Vec4,
    const float* __restrict__ Wref2,
    float* __restrict__ outp) {
  __shared__ float At[128][64];  // A transposed [k][row]
  __shared__ float Bs[128][64];  // B [k][col-half]
  const int rt = blockIdx.x;     // 0..249 row tiles of 64
  const int wy = blockIdx.y;     // 0..25
  const int mat = wy >> 1;       // 0..12 output slot
  const int ch = wy & 1;         // column half
  const int tid = threadIdx.x;

  const float* W;
  switch (mat >> 1) {
    case 0: W = Wref1; break;
    case 1: W = Vec1;  break;
    case 2: W = Wref3; break;
    case 3: W = Vec3;  break;
    case 4: W = Wref4; break;
    case 5: W = Vec4;  break;
    default: W = Wref2; break;
  }
  if (mat < 12) W += (size_t)(mat & 1) * (128 * 128);

  const float* asrc = enc + (size_t)rt * 64 * 128;
  for (int f = tid; f < 64 * 32; f += 256) {
    const int r = f >> 5, k4 = (f & 31) << 2;
    const float4 v = *(const float4*)(asrc + (size_t)r * 128 + k4);
    At[k4 + 0][r] = v.x; At[k4 + 1][r] = v.y;
    At[k4 + 2][r] = v.z; At[k4 + 3][r] = v.w;
  }
  for (int f = tid; f < 128 * 16; f += 256) {
    const int k = f >> 4, c4 = (f & 15) << 2;
    *(float4*)&Bs[k][c4] = *(const float4*)(W + (size_t)k * 128 + ch * 64 + c4);
  }
  __syncthreads();

  const int tx = tid & 15, ty = tid >> 4;
  float acc[4][4] = {{0.f}};
  for (int k = 0; k < 128; ++k) {
    const float4 a = *(const float4*)&At[k][ty * 4];
    const float4 b = *(const float4*)&Bs[k][tx * 4];
    acc[0][0] += a.x * b.x; acc[0][1] += a.x * b.y; acc[0][2] += a.x * b.z; acc[0][3] += a.x * b.w;
    acc[1][0] += a.y * b.x; acc[1][1] += a.y * b.y; acc[1][2] += a.y * b.z; acc[1][3] += a.y * b.w;
    acc[2][0] += a.z * b.x; acc[2][1] += a.z * b.y; acc[2][2] += a.z * b.z; acc[2][3] += a.z * b.w;
    acc[3][0] += a.w * b.x; acc[3][1] += a.w * b.y; acc[3][2] += a.w * b.z; acc[3][3] += a.w * b.w;
  }
  float* dst = outp + (size_t)mat * TPT + ((size_t)rt * 64 + ty * 4) * 128 + ch * 64 + tx * 4;
  for (int i = 0; i < 4; ++i) {
    float4 v; v.x = acc[i][0]; v.y = acc[i][1]; v.z = acc[i][2]; v.w = acc[i][3];
    *(float4*)(dst + (size_t)i * 128) = v;
  }
}

// ------------------------------------------------------------------- decode
__global__ __launch_bounds__(1024, 4) void ptr1_decode_kernel(
    const float* __restrict__ enc, const float* __restrict__ mask0,
    const float* __restrict__ Wq1, const float* __restrict__ Wq3,
    const float* __restrict__ Wq4, const float* __restrict__ Wmh,
    const float* __restrict__ Wq2, const float* __restrict__ Vec2,
    const float* __restrict__ dec_inp, const float* __restrict__ proj,
    float* __restrict__ partials, int* __restrict__ counters,
    float* __restrict__ out) {
  const int g = blockIdx.x >> 4;   // batch / group
  const int c = blockIdx.x & 15;   // block within group
  const int tid = threadIdx.x;
  const int wv = tid >> 6;         // wave 0..15
  const int lane = tid & 63;
  const int half = lane >> 5;      // 32-lane half handles one row
  const int hl = lane & 31;
  const int h0 = hl << 2;          // 4 h-elems per lane
  const int start = c * 63;
  const int cnt = min(63, Nn - start);
  const int jrow = wv * 2 + half;  // 0..31, stride 32 over rows

  __shared__ __align__(16) float hmean[128];
  __shared__ __align__(16) float qcur[256];
  __shared__ __align__(16) float qm[2][128];
  __shared__ __align__(16) float gf[256];
  __shared__ __align__(16) float vecl[128];
  __shared__ __align__(16) float wpart[NW][2][132];
  __shared__ __align__(16) float qpart[4][256];
  __shared__ __align__(16) float mpart[8][128];
  __shared__ float maskl[64];
  __shared__ float ulocal[64];
  __shared__ int sel_sh;
  __shared__ float logZ_sh;

  if (tid < 128) vecl[tid] = Vec2[tid];
  for (int j = tid; j < cnt; j += TPB) maskl[j] = mask0[(size_t)g * Nn + start + j];

  // ---- phase 0: h_mean = mean_n enc[g,n,:] ----
  {
    float4 a = {0.f, 0.f, 0.f, 0.f};
    const float* eb = enc + ((size_t)g * Nn + start) * Hh + h0;
    for (int j = jrow; j < cnt; j += 32) {
      const float4 e4 = *(const float4*)(eb + (size_t)j * Hh);
      a.x += e4.x; a.y += e4.y; a.z += e4.z; a.w += e4.w;
    }
    a.x += __shfl_xor(a.x, 32, 64); a.y += __shfl_xor(a.y, 32, 64);
    a.z += __shfl_xor(a.z, 32, 64); a.w += __shfl_xor(a.w, 32, 64);
    if (half == 0) *(float4*)&wpart[wv][0][4 + h0] = a;
    __syncthreads();
    if (tid < 128) {
      float s = 0.f;
      for (int w = 0; w < NW; ++w) s += wpart[w][0][4 + tid];
      partials[PPART(0, g, c, 0) + 4 + tid] = s;
    }
    group_barrier(&counters[0 * 16 + g], tid);
    if (tid < 128) {
      float s = 0.f;
      for (int cc = 0; cc < 16; ++cc) s += partials[PPART(0, g, cc, 0) + 4 + tid];
      hmean[tid] = s * (1.0f / (float)Nn);
    }
    __syncthreads();
  }

  int sel = -1;
  int p = 1;
  for (int step = 0; step < Ss; ++step) {
    // q0 = concat(h_mean, prev)
    if (tid < 128) {
      qcur[tid] = hmean[tid];
    } else if (tid < 256) {
      const int h = tid - 128;
      qcur[tid] = (step == 0) ? dec_inp[h] : enc[((size_t)g * Nn + sel) * Hh + h];
    }
    __syncthreads();

    for (int gl = 0; gl < 3; ++gl) {
      const float* Wq = (gl == 0) ? Wq1 : ((gl == 1) ? Wq3 : Wq4);
      const int Din = (gl == 0) ? 256 : 128;
      {  // q[m][h] = sum_i qcur[i] * Wq[m,i,h] — 4 partial threads per output
        const int o = tid & 255, part = tid >> 8;  // 0..3
        const int m = o >> 7, h = o & 127;
        const int seg = Din >> 2;  // 64 or 32
        float acc = 0.f;
        const float* wp = Wq + (size_t)m * Din * 128 + (size_t)part * seg * 128 + h;
        const float* qc = qcur + part * seg;
#pragma unroll 4
        for (int i = 0; i < seg; ++i) acc += qc[i] * wp[(size_t)i * 128];
        qpart[part][o] = acc;
      }
      __syncthreads();
      if (tid < 256) {
        const int m = tid >> 7, h = tid & 127;
        qm[m][h] = qpart[0][tid] + qpart[1][tid] + qpart[2][tid] + qpart[3][tid];
      }
      __syncthreads();

      const float4 qa = *(const float4*)&qm[0][h0];
      const float4 qb = *(const float4*)&qm[1][h0];
      const size_t rowb = ((size_t)g * Nn + start) * Hh + h0;
      const float* r0p = proj + (size_t)(4 * gl + 0) * TPT + rowb;
      const float* r1p = proj + (size_t)(4 * gl + 1) * TPT + rowb;
      const float* v0p = proj + (size_t)(4 * gl + 2) * TPT + rowb;
      const float* v1p = proj + (size_t)(4 * gl + 3) * TPT + rowb;
      float S0 = 0.f, S1 = 0.f;
      float4 g0 = {0.f, 0.f, 0.f, 0.f}, g1 = {0.f, 0.f, 0.f, 0.f};
      for (int j = jrow; j < cnt; j += 32) {
        const size_t off = (size_t)j * Hh;
        const float4 r0 = *(const float4*)(r0p + off);
        const float4 v0 = *(const float4*)(v0p + off);
        const float4 r1 = *(const float4*)(r1p + off);
        const float4 v1 = *(const float4*)(v1p + off);
        const float ml = maskl[j];
        float s0 = tanhf(qa.x + r0.x) * v0.x + tanhf(qa.y + r0.y) * v0.y +
                   tanhf(qa.z + r0.z) * v0.z + tanhf(qa.w + r0.w) * v0.w;
        float s1 = tanhf(qb.x + r1.x) * v1.x + tanhf(qb.y + r1.y) * v1.y +
                   tanhf(qb.z + r1.z) * v1.z + tanhf(qb.w + r1.w) * v1.w;
        red5_2(s0, s1);  // 32-lane sums (one row per half-wave)
        s0 = 10.f * tanhf(s0) - 1e8f * ml;
        s1 = 10.f * tanhf(s1) - 1e8f * ml;
        const float e0 = expf(s0 - 10.f);  // fixed max: scores are in [-10,10]
        const float e1 = expf(s1 - 10.f);
        S0 += e0; S1 += e1;
        g0.x += e0 * r0.x; g0.y += e0 * r0.y; g0.z += e0 * r0.z; g0.w += e0 * r0.w;
        g1.x += e1 * r1.x; g1.y += e1 * r1.y; g1.z += e1 * r1.z; g1.w += e1 * r1.w;
      }
      // combine halves (same h, different rows)
      S0 += __shfl_xor(S0, 32, 64); S1 += __shfl_xor(S1, 32, 64);
      g0.x += __shfl_xor(g0.x, 32, 64); g0.y += __shfl_xor(g0.y, 32, 64);
      g0.z += __shfl_xor(g0.z, 32, 64); g0.w += __shfl_xor(g0.w, 32, 64);
      g1.x += __shfl_xor(g1.x, 32, 64); g1.y += __shfl_xor(g1.y, 32, 64);
      g1.z += __shfl_xor(g1.z, 32, 64); g1.w += __shfl_xor(g1.w, 32, 64);
      if (half == 0) {
        *(float4*)&wpart[wv][0][4 + h0] = g0;
        *(float4*)&wpart[wv][1][4 + h0] = g1;
        if (hl == 0) { wpart[wv][0][0] = S0; wpart[wv][1][0] = S1; }
      }
      __syncthreads();
      const int par = p & 1;
      if (tid < 256) {  // block combine -> global partial
        const int m = tid >> 7, h = tid & 127;
        float gs = 0.f;
        for (int w = 0; w < NW; ++w) gs += wpart[w][m][4 + h];
        float* gp = partials + PPART(par, g, c, m);
        gp[4 + h] = gs;
        if (h == 0) {
          float ss = 0.f;
          for (int w = 0; w < NW; ++w) ss += wpart[w][m][0];
          gp[0] = ss;
        }
      }
      group_barrier(&counters[p * 16 + g], tid);
      if (tid < 256) {  // group combine (redundant per block, deterministic)
        const int m = tid >> 7, h = tid & 127;
        float Sx = 0.f, gx = 0.f;
        for (int cc = 0; cc < 16; ++cc) {
          const float* gp = partials + PPART(par, g, cc, m);
          Sx += gp[0];
          gx += gp[4 + h];
        }
        gf[m * 128 + h] = gx / Sx;  // softmax-weighted glimpse
      }
      p++;
      __syncthreads();
      {  // merge heads: qnext = g_flat @ Wmh — 8 partial threads per output
        const int h = tid & 127, part = tid >> 7;  // 0..7
        float acc = 0.f;
        const float* wp = Wmh + (size_t)part * 32 * 128 + h;
        const float* gg = gf + part * 32;
#pragma unroll 4
        for (int i = 0; i < 32; ++i) acc += gg[i] * wp[(size_t)i * 128];
        mpart[part][h] = acc;
      }
      __syncthreads();
      if (tid < 128) {
        float acc = 0.f;
        for (int w = 0; w < 8; ++w) acc += mpart[w][tid];
        qcur[tid] = acc;
      }
      __syncthreads();
    }

    // ---- pointer ----
    {
      const int h = tid & 127, part = tid >> 7;  // 8 parts x 16 terms
      float acc = 0.f;
      const float* wp = Wq2 + (size_t)part * 16 * 128 + h;
      const float* qc = qcur + part * 16;
#pragma unroll 4
      for (int i = 0; i < 16; ++i) acc += qc[i] * wp[(size_t)i * 128];
      mpart[part][h] = acc;
    }
    __syncthreads();
    if (tid < 128) {
      float acc = 0.f;
      for (int w = 0; w < 8; ++w) acc += mpart[w][tid];
      qm[0][tid] = acc;
    }
    __syncthreads();
    {
      const float4 q2 = *(const float4*)&qm[0][h0];
      const float4 vz = *(const float4*)&vecl[h0];
      const float* r2p = proj + (size_t)12 * TPT + ((size_t)g * Nn + start) * Hh + h0;
      float Sv = 0.f, um = -3.0e38f; int ui = 0x7fffffff;
      for (int j = jrow; j < cnt; j += 32) {
        const float4 rr = *(const float4*)(r2p + (size_t)j * Hh);
        float up = tanhf(q2.x + rr.x) * vz.x + tanhf(q2.y + rr.y) * vz.y +
                   tanhf(q2.z + rr.z) * vz.z + tanhf(q2.w + rr.w) * vz.w;
        up = red5(up);
        const float u = 10.f * tanhf(up) - 1e8f * maskl[j];
        if (hl == 0) ulocal[j] = u;
        Sv += expf(u - 10.f);
        if (u > um) { um = u; ui = start + j; }  // '>' keeps first index
      }
      Sv += __shfl_xor(Sv, 32, 64);
      const float um2 = __shfl_xor(um, 32, 64);
      const int ui2 = __shfl_xor(ui, 32, 64);
      if (um2 > um || (um2 == um && ui2 < ui)) { um = um2; ui = ui2; }
      if (lane == 0) {
        wpart[wv][0][0] = Sv; wpart[wv][0][1] = um;
        wpart[wv][0][2] = __int_as_float(ui);
      }
    }
    __syncthreads();
    const int par = p & 1;
    if (tid == 0) {
      float St = 0.f, bm = -3.0e38f; int bi = 0x7fffffff;
      for (int ww = 0; ww < NW; ++ww) {
        St += wpart[ww][0][0];
        const float m2 = wpart[ww][0][1];
        const int i2 = __float_as_int(wpart[ww][0][2]);
        if (m2 > bm || (m2 == bm && i2 < bi)) { bm = m2; bi = i2; }
      }
      float* gp = partials + PPART(par, g, c, 0);
      gp[0] = St; gp[1] = bm; gp[2] = __int_as_float(bi);
    }
    group_barrier(&counters[p * 16 + g], tid);
    if (tid == 0) {
      float St = 0.f, bm = -3.0e38f; int bi = 0x7fffffff;
      for (int cc = 0; cc < 16; ++cc) {
        const float* gp = partials + PPART(par, g, cc, 0);
        St += gp[0];
        const float m2 = gp[1];
        const int i2 = __float_as_int(gp[2]);
        if (m2 > bm || (m2 == bm && i2 < bi)) { bm = m2; bi = i2; }
      }
      sel_sh = bi;
      logZ_sh = 10.f + logf(St);  // logsumexp with fixed shift 10
    }
    p++;
    __syncthreads();
    sel = sel_sh;
    const float lz = logZ_sh;
    for (int j = tid; j < cnt; j += TPB)
      out[(size_t)step * (Bb * Nn) + (size_t)g * Nn + start + j] = ulocal[j] - lz;
    if (c == 0 && tid == 0)
      out[(size_t)Ss * Bb * Nn + (size_t)step * Bb + g] = (float)sel;
    if (tid == 0 && sel >= start && sel < start + cnt) maskl[sel - start] = 1.0f;
    __syncthreads();
  }
}

// -------------------------------------------------------------------- launch
extern "C" void kernel_launch(void* const* d_in, const int* in_sizes, int n_in,
                              void* d_out, int out_size, void* d_ws, size_t ws_size,
                              hipStream_t stream) {
  const float* enc     = (const float*)d_in[0];
  const float* mask0   = (const float*)d_in[1];
  const float* Wq1     = (const float*)d_in[2];
  const float* Wref1   = (const float*)d_in[3];
  const float* Vec1    = (const float*)d_in[4];
  const float* Wq3     = (const float*)d_in[5];
  const float* Wref3   = (const float*)d_in[6];
  const float* Vec3    = (const float*)d_in[7];
  const float* Wq4     = (const float*)d_in[8];
  const float* Wref4   = (const float*)d_in[9];
  const float* Vec4    = (const float*)d_in[10];
  const float* Wmh     = (const float*)d_in[11];
  const float* Wq2     = (const float*)d_in[12];
  const float* Wref2   = (const float*)d_in[13];
  const float* Vec2    = (const float*)d_in[14];
  const float* dec_inp = (const float*)d_in[15];
  float* out = (float*)d_out;

  char* ws = (char*)d_ws;
  int* counters   = (int*)ws;                       // 65*16 ints, < 8 KB
  float* partials = (float*)(ws + 8192);            // 540,672 B
  float* proj     = (float*)(ws + 548864);          // 13 * 2,048,000 f32

  hipMemsetAsync(counters, 0, 8192, stream);

  dim3 pg(250, 26);
  ptr1_proj_kernel<<<pg, 256, 0, stream>>>(enc, Wref1, Vec1, Wref3, Vec3,
                                           Wref4, Vec4, Wref2, proj);

  void* args[] = {(void*)&enc,  (void*)&mask0, (void*)&Wq1, (void*)&Wq3,
                  (void*)&Wq4,  (void*)&Wmh,   (void*)&Wq2, (void*)&Vec2,
                  (void*)&dec_inp, (void*)&proj, (void*)&partials,
                  (void*)&counters, (void*)&out};
  hipLaunchCooperativeKernel((const void*)ptr1_decode_kernel, dim3(256),
                             dim3(1024), args, 0, stream);
}

// Round 4
// 1595.565 us; speedup vs baseline: 2.5954x; 1.2160x over previous
//
#include <hip/hip_runtime.h>

// PtrNet greedy decode, B=16, N=1000, H=128, M=2, 16 steps.
// Phase 1: proj_kernel — 13x [16000x128]@[128x128] f32 GEMM into ws.
// Phase 2: decode_kernel — persistent cooperative kernel, 16 groups (one per
//          batch) x 16 blocks x 1024 threads (known-good cooperative grid),
//          FENCE-FREE group barriers (partials via agent-scope atomics),
//          fast tanh (v_exp+rcp), 2-row fully-unrolled streaming phases.

#define Bb 16
#define Nn 1000
#define Hh 128
#define Ss 16
#define TPB 1024
#define NW 16                 // waves per block
#define NB 16                 // blocks per group
#define ROWS 63               // rows per block
#define TPT (Nn * Bb * Hh)    // elems per projection tensor slot: 2,048,000

// partials slot: [par][g][c][m][132]; [0..2] scalars, [4+h] vector payload
#define PPART(par, g, c, m) \
  ((((size_t)(par)*16 + (size_t)(g))*NB + (size_t)(c))*2 + (size_t)(m))*132

__device__ __forceinline__ void red5_2(float& a, float& b) {
#pragma unroll
  for (int m = 1; m <= 16; m <<= 1) {
    a += __shfl_xor(a, m, 64);
    b += __shfl_xor(b, m, 64);
  }
}
__device__ __forceinline__ void red5_4(float& a, float& b, float& c, float& d) {
#pragma unroll
  for (int m = 1; m <= 16; m <<= 1) {
    a += __shfl_xor(a, m, 64);
    b += __shfl_xor(b, m, 64);
    c += __shfl_xor(c, m, 64);
    d += __shfl_xor(d, m, 64);
  }
}

// fast tanh: (e-1)/(e+1), e=exp(2x), clamped so v_exp never overflows.
// |err| ~1e-7 vs tanhf; logit gaps are ~1e-1 so sel decisions are safe.
__device__ __forceinline__ float tanh_fast(float x) {
  const float xc = fminf(fmaxf(x, -10.f), 10.f);
  const float e = __expf(xc + xc);
  return (e - 1.f) * __builtin_amdgcn_rcpf(e + 1.f);
}
__device__ __forceinline__ float dot4t(const float4 q, const float4 r, const float4 v) {
  return tanh_fast(q.x + r.x) * v.x + tanh_fast(q.y + r.y) * v.y +
         tanh_fast(q.z + r.z) * v.z + tanh_fast(q.w + r.w) * v.w;
}

// agent-coherent access (goes to the coherence point; no fences needed)
__device__ __forceinline__ float aload(const float* p) {
  return __hip_atomic_load(p, __ATOMIC_RELAXED, __HIP_MEMORY_SCOPE_AGENT);
}
__device__ __forceinline__ void astore(float* p, float v) {
  __hip_atomic_store(p, v, __ATOMIC_RELAXED, __HIP_MEMORY_SCOPE_AGENT);
}

// Fence-free group barrier: data moves via agent-scope atomics; RELEASE on the
// counter orders the writer's stores; readers issue loads only after the
// poll-exit + __syncthreads (in-order issue, no speculation past the branch).
__device__ __forceinline__ void group_barrier(int* cnt, int tid) {
  __syncthreads();
  if (tid == 0) {
    __hip_atomic_fetch_add(cnt, 1, __ATOMIC_RELEASE, __HIP_MEMORY_SCOPE_AGENT);
    while (__hip_atomic_load(cnt, __ATOMIC_RELAXED, __HIP_MEMORY_SCOPE_AGENT) < NB)
      __builtin_amdgcn_s_sleep(2);
  }
  __syncthreads();
}

// ---------------------------------------------------------------- projections
__global__ __launch_bounds__(256) void ptr1_proj_kernel(
    const float* __restrict__ enc,
    const float* __restrict__ Wref1, const float* __restrict__ Vec1,
    const float* __restrict__ Wref3, const float* __restrict__ Vec3,
    const float* __restrict__ Wref4, const float* __restrict__ Vec4,
    const float* __restrict__ Wref2,
    float* __restrict__ outp) {
  __shared__ float At[128][64];  // A transposed [k][row]
  __shared__ float Bs[128][64];  // B [k][col-half]
  const int rt = blockIdx.x;     // 0..249 row tiles of 64
  const int wy = blockIdx.y;     // 0..25
  const int mat = wy >> 1;       // 0..12 output slot
  const int ch = wy & 1;         // column half
  const int tid = threadIdx.x;

  const float* W;
  switch (mat >> 1) {
    case 0: W = Wref1; break;
    case 1: W = Vec1;  break;
    case 2: W = Wref3; break;
    case 3: W = Vec3;  break;
    case 4: W = Wref4; break;
    case 5: W = Vec4;  break;
    default: W = Wref2; break;
  }
  if (mat < 12) W += (size_t)(mat & 1) * (128 * 128);

  const float* asrc = enc + (size_t)rt * 64 * 128;
  for (int f = tid; f < 64 * 32; f += 256) {
    const int r = f >> 5, k4 = (f & 31) << 2;
    const float4 v = *(const float4*)(asrc + (size_t)r * 128 + k4);
    At[k4 + 0][r] = v.x; At[k4 + 1][r] = v.y;
    At[k4 + 2][r] = v.z; At[k4 + 3][r] = v.w;
  }
  for (int f = tid; f < 128 * 16; f += 256) {
    const int k = f >> 4, c4 = (f & 15) << 2;
    *(float4*)&Bs[k][c4] = *(const float4*)(W + (size_t)k * 128 + ch * 64 + c4);
  }
  __syncthreads();

  const int tx = tid & 15, ty = tid >> 4;
  float acc[4][4] = {{0.f}};
  for (int k = 0; k < 128; ++k) {
    const float4 a = *(const float4*)&At[k][ty * 4];
    const float4 b = *(const float4*)&Bs[k][tx * 4];
    acc[0][0] += a.x * b.x; acc[0][1] += a.x * b.y; acc[0][2] += a.x * b.z; acc[0][3] += a.x * b.w;
    acc[1][0] += a.y * b.x; acc[1][1] += a.y * b.y; acc[1][2] += a.y * b.z; acc[1][3] += a.y * b.w;
    acc[2][0] += a.z * b.x; acc[2][1] += a.z * b.y; acc[2][2] += a.z * b.z; acc[2][3] += a.z * b.w;
    acc[3][0] += a.w * b.x; acc[3][1] += a.w * b.y; acc[3][2] += a.w * b.z; acc[3][3] += a.w * b.w;
  }
  float* dst = outp + (size_t)mat * TPT + ((size_t)rt * 64 + ty * 4) * 128 + ch * 64 + tx * 4;
  for (int i = 0; i < 4; ++i) {
    float4 v; v.x = acc[i][0]; v.y = acc[i][1]; v.z = acc[i][2]; v.w = acc[i][3];
    *(float4*)(dst + (size_t)i * 128) = v;
  }
}

// ------------------------------------------------------------------- decode
__global__ __launch_bounds__(1024, 4) void ptr1_decode_kernel(
    const float* __restrict__ enc, const float* __restrict__ mask0,
    const float* __restrict__ Wq1, const float* __restrict__ Wq3,
    const float* __restrict__ Wq4, const float* __restrict__ Wmh,
    const float* __restrict__ Wq2, const float* __restrict__ Vec2,
    const float* __restrict__ dec_inp, const float* __restrict__ proj,
    float* __restrict__ partials, int* __restrict__ counters,
    float* __restrict__ out) {
  const int g = blockIdx.x >> 4;   // batch / group
  const int c = blockIdx.x & 15;   // block within group
  const int tid = threadIdx.x;
  const int wv = tid >> 6;         // wave 0..15
  const int lane = tid & 63;
  const int half = lane >> 5;      // 32-lane half handles one row
  const int hl = lane & 31;
  const int h0 = hl << 2;          // 4 h-elems per lane
  const int start = c * ROWS;
  const int cnt = min(ROWS, Nn - start);   // 63, last block 55
  const int jrow = wv * 2 + half;          // 0..31 (always < cnt)
  const int j2 = jrow + 32;                // second row, guarded
  const bool a2 = j2 < cnt;
  const int j2c = a2 ? j2 : jrow;          // safe index for loads

  __shared__ __align__(16) float hmean[128];
  __shared__ __align__(16) float qcur[256];
  __shared__ __align__(16) float qm[2][128];
  __shared__ __align__(16) float gf[256];
  __shared__ __align__(16) float vecl[128];
  __shared__ __align__(16) float wpart[NW][2][132];
  __shared__ __align__(16) float qpart[4][256];
  __shared__ __align__(16) float mpart[8][128];
  __shared__ float spart[4][2];
  __shared__ float maskl[64];
  __shared__ float ulocal[64];
  __shared__ int sel_sh;
  __shared__ float logZ_sh;

  if (tid < 128) vecl[tid] = Vec2[tid];
  for (int j = tid; j < cnt; j += TPB) maskl[j] = mask0[(size_t)g * Nn + start + j];

  const size_t o1 = (size_t)jrow * Hh;
  const size_t o2 = (size_t)j2c * Hh;

  // ---- phase 0: h_mean = mean_n enc[g,n,:] ----
  {
    const float* eb = enc + ((size_t)g * Nn + start) * Hh + h0;
    const float4 eA = *(const float4*)(eb + o1);
    const float4 eB = *(const float4*)(eb + o2);
    float4 a;
    a.x = eA.x + (a2 ? eB.x : 0.f); a.y = eA.y + (a2 ? eB.y : 0.f);
    a.z = eA.z + (a2 ? eB.z : 0.f); a.w = eA.w + (a2 ? eB.w : 0.f);
    a.x += __shfl_xor(a.x, 32, 64); a.y += __shfl_xor(a.y, 32, 64);
    a.z += __shfl_xor(a.z, 32, 64); a.w += __shfl_xor(a.w, 32, 64);
    if (half == 0) *(float4*)&wpart[wv][0][4 + h0] = a;
    __syncthreads();
    if (tid < 128) {
      float s = 0.f;
      for (int w = 0; w < NW; ++w) s += wpart[w][0][4 + tid];
      astore(&partials[PPART(0, g, c, 0) + 4 + tid], s);
    }
    group_barrier(&counters[0 * 16 + g], tid);
    if (tid < 128) {
      float s = 0.f;
#pragma unroll 8
      for (int cc = 0; cc < NB; ++cc) s += aload(&partials[PPART(0, g, cc, 0) + 4 + tid]);
      hmean[tid] = s * (1.0f / (float)Nn);
    }
    __syncthreads();
  }

  int sel = -1;
  int p = 1;
  for (int step = 0; step < Ss; ++step) {
    // q0 = concat(h_mean, prev)
    if (tid < 128) {
      qcur[tid] = hmean[tid];
    } else if (tid < 256) {
      const int h = tid - 128;
      qcur[tid] = (step == 0) ? dec_inp[h] : enc[((size_t)g * Nn + sel) * Hh + h];
    }
    __syncthreads();

    for (int gl = 0; gl < 3; ++gl) {
      const float* Wq = (gl == 0) ? Wq1 : ((gl == 1) ? Wq3 : Wq4);
      const int Din = (gl == 0) ? 256 : 128;
      {  // q[m][h] = sum_i qcur[i] * Wq[m,i,h] — 4 partial threads per output
        const int o = tid & 255, part = tid >> 8;  // 0..3
        const int m = o >> 7, h = o & 127;
        const int seg = Din >> 2;  // 64 or 32
        float acc = 0.f;
        const float* wp = Wq + (size_t)m * Din * 128 + (size_t)part * seg * 128 + h;
        const float* qc = qcur + part * seg;
#pragma unroll 8
        for (int i = 0; i < seg; ++i) acc += qc[i] * wp[(size_t)i * 128];
        qpart[part][o] = acc;
      }
      __syncthreads();
      if (tid < 256) {
        const int m = tid >> 7, h = tid & 127;
        qm[m][h] = qpart[0][tid] + qpart[1][tid] + qpart[2][tid] + qpart[3][tid];
      }
      __syncthreads();

      const float4 qa = *(const float4*)&qm[0][h0];
      const float4 qb = *(const float4*)&qm[1][h0];
      const size_t rowb = ((size_t)g * Nn + start) * Hh + h0;
      const float* r0p = proj + (size_t)(4 * gl + 0) * TPT + rowb;
      const float* r1p = proj + (size_t)(4 * gl + 1) * TPT + rowb;
      const float* v0p = proj + (size_t)(4 * gl + 2) * TPT + rowb;
      const float* v1p = proj + (size_t)(4 * gl + 3) * TPT + rowb;
      // two rows fully unrolled; 8 float4 loads issued up front
      const float4 r0A = *(const float4*)(r0p + o1), r0B = *(const float4*)(r0p + o2);
      const float4 r1A = *(const float4*)(r1p + o1), r1B = *(const float4*)(r1p + o2);
      const float4 v0A = *(const float4*)(v0p + o1), v0B = *(const float4*)(v0p + o2);
      const float4 v1A = *(const float4*)(v1p + o1), v1B = *(const float4*)(v1p + o2);
      const float mlA = maskl[jrow], mlB = maskl[j2c];
      float s0A = dot4t(qa, r0A, v0A), s1A = dot4t(qb, r1A, v1A);
      float s0B = dot4t(qa, r0B, v0B), s1B = dot4t(qb, r1B, v1B);
      red5_4(s0A, s1A, s0B, s1B);  // 32-lane row sums, 4 chains interleaved
      s0A = 10.f * tanh_fast(s0A) - 1e8f * mlA;
      s1A = 10.f * tanh_fast(s1A) - 1e8f * mlA;
      s0B = 10.f * tanh_fast(s0B) - 1e8f * mlB;
      s1B = 10.f * tanh_fast(s1B) - 1e8f * mlB;
      const float e0A = __expf(s0A - 10.f), e1A = __expf(s1A - 10.f);
      const float e0B = a2 ? __expf(s0B - 10.f) : 0.f;
      const float e1B = a2 ? __expf(s1B - 10.f) : 0.f;
      float S0 = e0A + e0B, S1 = e1A + e1B;
      float4 g0, g1;
      g0.x = e0A * r0A.x + e0B * r0B.x; g0.y = e0A * r0A.y + e0B * r0B.y;
      g0.z = e0A * r0A.z + e0B * r0B.z; g0.w = e0A * r0A.w + e0B * r0B.w;
      g1.x = e1A * r1A.x + e1B * r1B.x; g1.y = e1A * r1A.y + e1B * r1B.y;
      g1.z = e1A * r1A.z + e1B * r1B.z; g1.w = e1A * r1A.w + e1B * r1B.w;
      // combine halves (same h, different rows)
      S0 += __shfl_xor(S0, 32, 64); S1 += __shfl_xor(S1, 32, 64);
      g0.x += __shfl_xor(g0.x, 32, 64); g0.y += __shfl_xor(g0.y, 32, 64);
      g0.z += __shfl_xor(g0.z, 32, 64); g0.w += __shfl_xor(g0.w, 32, 64);
      g1.x += __shfl_xor(g1.x, 32, 64); g1.y += __shfl_xor(g1.y, 32, 64);
      g1.z += __shfl_xor(g1.z, 32, 64); g1.w += __shfl_xor(g1.w, 32, 64);
      if (half == 0) {
        *(float4*)&wpart[wv][0][4 + h0] = g0;
        *(float4*)&wpart[wv][1][4 + h0] = g1;
        if (hl == 0) { wpart[wv][0][0] = S0; wpart[wv][1][0] = S1; }
      }
      __syncthreads();
      const int par = p & 1;
      if (tid < 256) {  // block combine -> global partial
        const int m = tid >> 7, h = tid & 127;
        float gs = 0.f;
        for (int w = 0; w < NW; ++w) gs += wpart[w][m][4 + h];
        float* gp = partials + PPART(par, g, c, m);
        astore(&gp[4 + h], gs);
        if (h == 0) {
          float ss = 0.f;
          for (int w = 0; w < NW; ++w) ss += wpart[w][m][0];
          astore(&gp[0], ss);
        }
      }
      group_barrier(&counters[p * 16 + g], tid);
      {  // group combine, 4-way split over cc across all 1024 threads
        const int p4 = tid >> 8, o = tid & 255;
        const int m = o >> 7, h = o & 127;
        const int c0 = p4 * 4;
        float gx = 0.f;
#pragma unroll
        for (int cc = c0; cc < c0 + 4; ++cc)
          gx += aload(&partials[PPART(par, g, cc, m) + 4 + h]);
        qpart[p4][o] = gx;
        if (h == 0) {
          float Sx = 0.f;
#pragma unroll
          for (int cc = c0; cc < c0 + 4; ++cc)
            Sx += aload(&partials[PPART(par, g, cc, m)]);
          spart[p4][m] = Sx;
        }
      }
      p++;
      __syncthreads();
      if (tid < 256) {
        const int m = tid >> 7;
        const float gx = qpart[0][tid] + qpart[1][tid] + qpart[2][tid] + qpart[3][tid];
        const float Sx = spart[0][m] + spart[1][m] + spart[2][m] + spart[3][m];
        gf[tid] = gx / Sx;  // softmax-weighted glimpse
      }
      __syncthreads();
      {  // merge heads: qnext = g_flat @ Wmh — 8 partial threads per output
        const int h = tid & 127, part = tid >> 7;  // 0..7
        float acc = 0.f;
        const float* wp = Wmh + (size_t)part * 32 * 128 + h;
        const float* gg = gf + part * 32;
#pragma unroll 8
        for (int i = 0; i < 32; ++i) acc += gg[i] * wp[(size_t)i * 128];
        mpart[part][h] = acc;
      }
      __syncthreads();
      if (tid < 128) {
        float acc = 0.f;
        for (int w = 0; w < 8; ++w) acc += mpart[w][tid];
        qcur[tid] = acc;
      }
      __syncthreads();
    }

    // ---- pointer ----
    {
      const int h = tid & 127, part = tid >> 7;  // 8 parts x 16 terms
      float acc = 0.f;
      const float* wp = Wq2 + (size_t)part * 16 * 128 + h;
      const float* qc = qcur + part * 16;
#pragma unroll 8
      for (int i = 0; i < 16; ++i) acc += qc[i] * wp[(size_t)i * 128];
      mpart[part][h] = acc;
    }
    __syncthreads();
    if (tid < 128) {
      float acc = 0.f;
      for (int w = 0; w < 8; ++w) acc += mpart[w][tid];
      qm[0][tid] = acc;
    }
    __syncthreads();
    {
      const float4 q2 = *(const float4*)&qm[0][h0];
      const float4 vz = *(const float4*)&vecl[h0];
      const float* r2p = proj + (size_t)12 * TPT + ((size_t)g * Nn + start) * Hh + h0;
      const float4 rrA = *(const float4*)(r2p + o1);
      const float4 rrB = *(const float4*)(r2p + o2);
      float upA = dot4t(q2, rrA, vz);
      float upB = dot4t(q2, rrB, vz);
      red5_2(upA, upB);
      const float mlA = maskl[jrow], mlB = maskl[j2c];
      const float uA = 10.f * tanh_fast(upA) - 1e8f * mlA;
      const float uB = a2 ? (10.f * tanh_fast(upB) - 1e8f * mlB) : -3.0e38f;
      if (hl == 0) {
        ulocal[jrow] = uA;
        if (a2) ulocal[j2] = uB;
      }
      float Sv = __expf(uA - 10.f) + (a2 ? __expf(uB - 10.f) : 0.f);
      float um = uA; int ui = start + jrow;
      if (a2 && uB > um) { um = uB; ui = start + j2; }  // j2>jrow: '>' keeps first
      Sv += __shfl_xor(Sv, 32, 64);
      const float um2 = __shfl_xor(um, 32, 64);
      const int ui2 = __shfl_xor(ui, 32, 64);
      if (um2 > um || (um2 == um && ui2 < ui)) { um = um2; ui = ui2; }
      if (lane == 0) {
        wpart[wv][0][0] = Sv; wpart[wv][0][1] = um;
        wpart[wv][0][2] = __int_as_float(ui);
      }
    }
    __syncthreads();
    const int par = p & 1;
    if (tid == 0) {
      float St = 0.f, bm = -3.0e38f; int bi = 0x7fffffff;
      for (int ww = 0; ww < NW; ++ww) {
        St += wpart[ww][0][0];
        const float m2 = wpart[ww][0][1];
        const int i2 = __float_as_int(wpart[ww][0][2]);
        if (m2 > bm || (m2 == bm && i2 < bi)) { bm = m2; bi = i2; }
      }
      float* gp = partials + PPART(par, g, c, 0);
      astore(&gp[0], St); astore(&gp[1], bm);
      astore(&gp[2], __int_as_float(bi));
    }
    group_barrier(&counters[p * 16 + g], tid);
    if (tid == 0) {
      float St = 0.f, bm = -3.0e38f; int bi = 0x7fffffff;
      for (int cc = 0; cc < NB; ++cc) {
        const float* gp = partials + PPART(par, g, cc, 0);
        St += aload(&gp[0]);
        const float m2 = aload(&gp[1]);
        const int i2 = __float_as_int(aload(&gp[2]));
        if (m2 > bm || (m2 == bm && i2 < bi)) { bm = m2; bi = i2; }
      }
      sel_sh = bi;
      logZ_sh = 10.f + logf(St);  // logsumexp with fixed shift 10
    }
    p++;
    __syncthreads();
    sel = sel_sh;
    const float lz = logZ_sh;
    for (int j = tid; j < cnt; j += TPB)
      out[(size_t)step * (Bb * Nn) + (size_t)g * Nn + start + j] = ulocal[j] - lz;
    if (c == 0 && tid == 0)
      out[(size_t)Ss * Bb * Nn + (size_t)step * Bb + g] = (float)sel;
    if (tid == 0 && sel >= start && sel < start + cnt) maskl[sel - start] = 1.0f;
    __syncthreads();
  }
}

// -------------------------------------------------------------------- launch
extern "C" void kernel_launch(void* const* d_in, const int* in_sizes, int n_in,
                              void* d_out, int out_size, void* d_ws, size_t ws_size,
                              hipStream_t stream) {
  const float* enc     = (const float*)d_in[0];
  const float* mask0   = (const float*)d_in[1];
  const float* Wq1     = (const float*)d_in[2];
  const float* Wref1   = (const float*)d_in[3];
  const float* Vec1    = (const float*)d_in[4];
  const float* Wq3     = (const float*)d_in[5];
  const float* Wref3   = (const float*)d_in[6];
  const float* Vec3    = (const float*)d_in[7];
  const float* Wq4     = (const float*)d_in[8];
  const float* Wref4   = (const float*)d_in[9];
  const float* Vec4    = (const float*)d_in[10];
  const float* Wmh     = (const float*)d_in[11];
  const float* Wq2     = (const float*)d_in[12];
  const float* Wref2   = (const float*)d_in[13];
  const float* Vec2    = (const float*)d_in[14];
  const float* dec_inp = (const float*)d_in[15];
  float* out = (float*)d_out;

  char* ws = (char*)d_ws;
  int* counters   = (int*)ws;                       // 65*16 ints, < 8 KB
  float* partials = (float*)(ws + 8192);            // 540,672 B
  float* proj     = (float*)(ws + 548864);          // 13 * 2,048,000 f32

  hipMemsetAsync(counters, 0, 8192, stream);

  dim3 pg(250, 26);
  ptr1_proj_kernel<<<pg, 256, 0, stream>>>(enc, Wref1, Vec1, Wref3, Vec3,
                                           Wref4, Vec4, Wref2, proj);

  void* args[] = {(void*)&enc,  (void*)&mask0, (void*)&Wq1, (void*)&Wq3,
                  (void*)&Wq4,  (void*)&Wmh,   (void*)&Wq2, (void*)&Vec2,
                  (void*)&dec_inp, (void*)&proj, (void*)&partials,
                  (void*)&counters, (void*)&out};
  hipLaunchCooperativeKernel((const void*)ptr1_decode_kernel, dim3(256),
                             dim3(1024), args, 0, stream);
}

// Round 5
// 1233.957 us; speedup vs baseline: 3.3560x; 1.2930x over previous
//
#include <hip/hip_runtime.h>

// PtrNet greedy decode, B=16, N=1000, H=128, M=2, 16 steps.
// Phase 1: proj_kernel — 13x [16000x128]@[128x128] f32 GEMM into ws.
// Phase 2: decode_kernel — persistent cooperative kernel, 16 groups (one per
//          batch) x 16 blocks x 1024 threads. Flag-array group barriers
//          (release store + parallel poll, no serialized RMW), agent-scope
//          atomic partials, hoisted streaming loads, fast tanh, and
//          hmean@Wq1_top precomputed once (glimpse-1 gemm shrunk to 128-dot).

#define Bb 16
#define Nn 1000
#define Hh 128
#define Ss 16
#define TPB 1024
#define NW 16                 // waves per block
#define NB 16                 // blocks per group
#define ROWS 63               // rows per block
#define TPT (Nn * Bb * Hh)    // elems per projection tensor slot: 2,048,000

// partials slot: [par][g][c][m][132]; [0..2] scalars, [4+h] vector payload
#define PPART(par, g, c, m) \
  ((((size_t)(par)*16 + (size_t)(g))*NB + (size_t)(c))*2 + (size_t)(m))*132

__device__ __forceinline__ void red5_2(float& a, float& b) {
#pragma unroll
  for (int m = 1; m <= 16; m <<= 1) {
    a += __shfl_xor(a, m, 64);
    b += __shfl_xor(b, m, 64);
  }
}
__device__ __forceinline__ void red5_4(float& a, float& b, float& c, float& d) {
#pragma unroll
  for (int m = 1; m <= 16; m <<= 1) {
    a += __shfl_xor(a, m, 64);
    b += __shfl_xor(b, m, 64);
    c += __shfl_xor(c, m, 64);
    d += __shfl_xor(d, m, 64);
  }
}

// fast tanh: (e-1)/(e+1), e=exp(2x), clamped so v_exp never overflows.
__device__ __forceinline__ float tanh_fast(float x) {
  const float xc = fminf(fmaxf(x, -10.f), 10.f);
  const float e = __expf(xc + xc);
  return (e - 1.f) * __builtin_amdgcn_rcpf(e + 1.f);
}
__device__ __forceinline__ float dot4t(const float4 q, const float4 r, const float4 v) {
  return tanh_fast(q.x + r.x) * v.x + tanh_fast(q.y + r.y) * v.y +
         tanh_fast(q.z + r.z) * v.z + tanh_fast(q.w + r.w) * v.w;
}

// agent-coherent access (coherence point; bypasses stale L1/L2)
__device__ __forceinline__ float aload(const float* p) {
  return __hip_atomic_load(p, __ATOMIC_RELAXED, __HIP_MEMORY_SCOPE_AGENT);
}
__device__ __forceinline__ void astore(float* p, float v) {
  __hip_atomic_store(p, v, __ATOMIC_RELAXED, __HIP_MEMORY_SCOPE_AGENT);
}

// Flag-array group barrier: block c release-stores monotonic phase id to its
// own 128B-strided flag; wave 0 polls all NB flags in parallel (one round
// trip). No serialized RMW, no cache-maintenance fences.
__device__ __forceinline__ void gbar(int* fl, int c, int p, int tid, int lane) {
  __syncthreads();
  if (tid < 64) {
    if (lane == 0)
      __hip_atomic_store(&fl[c * 32], p, __ATOMIC_RELEASE, __HIP_MEMORY_SCOPE_AGENT);
    int v = p;
    while (true) {
      if (lane < NB)
        v = __hip_atomic_load(&fl[lane * 32], __ATOMIC_RELAXED, __HIP_MEMORY_SCOPE_AGENT);
      if (__all(v >= p)) break;
      __builtin_amdgcn_s_sleep(1);
    }
  }
  __syncthreads();
}

// ---------------------------------------------------------------- projections
__global__ __launch_bounds__(256) void ptr1_proj_kernel(
    const float* __restrict__ enc,
    const float* __restrict__ Wref1, const float* __restrict__ Vec1,
    const float* __restrict__ Wref3, const float* __restrict__ Vec3,
    const float* __restrict__ Wref4, const float* __restrict__ Vec4,
    const float* __restrict__ Wref2,
    float* __restrict__ outp) {
  __shared__ float At[128][64];  // A transposed [k][row]
  __shared__ float Bs[128][64];  // B [k][col-half]
  const int rt = blockIdx.x;     // 0..249 row tiles of 64
  const int wy = blockIdx.y;     // 0..25
  const int mat = wy >> 1;       // 0..12 output slot
  const int ch = wy & 1;         // column half
  const int tid = threadIdx.x;

  const float* W;
  switch (mat >> 1) {
    case 0: W = Wref1; break;
    case 1: W = Vec1;  break;
    case 2: W = Wref3; break;
    case 3: W = Vec3;  break;
    case 4: W = Wref4; break;
    case 5: W = Vec4;  break;
    default: W = Wref2; break;
  }
  if (mat < 12) W += (size_t)(mat & 1) * (128 * 128);

  const float* asrc = enc + (size_t)rt * 64 * 128;
  for (int f = tid; f < 64 * 32; f += 256) {
    const int r = f >> 5, k4 = (f & 31) << 2;
    const float4 v = *(const float4*)(asrc + (size_t)r * 128 + k4);
    At[k4 + 0][r] = v.x; At[k4 + 1][r] = v.y;
    At[k4 + 2][r] = v.z; At[k4 + 3][r] = v.w;
  }
  for (int f = tid; f < 128 * 16; f += 256) {
    const int k = f >> 4, c4 = (f & 15) << 2;
    *(float4*)&Bs[k][c4] = *(const float4*)(W + (size_t)k * 128 + ch * 64 + c4);
  }
  __syncthreads();

  const int tx = tid & 15, ty = tid >> 4;
  float acc[4][4] = {{0.f}};
  for (int k = 0; k < 128; ++k) {
    const float4 a = *(const float4*)&At[k][ty * 4];
    const float4 b = *(const float4*)&Bs[k][tx * 4];
    acc[0][0] += a.x * b.x; acc[0][1] += a.x * b.y; acc[0][2] += a.x * b.z; acc[0][3] += a.x * b.w;
    acc[1][0] += a.y * b.x; acc[1][1] += a.y * b.y; acc[1][2] += a.y * b.z; acc[1][3] += a.y * b.w;
    acc[2][0] += a.z * b.x; acc[2][1] += a.z * b.y; acc[2][2] += a.z * b.z; acc[2][3] += a.z * b.w;
    acc[3][0] += a.w * b.x; acc[3][1] += a.w * b.y; acc[3][2] += a.w * b.z; acc[3][3] += a.w * b.w;
  }
  float* dst = outp + (size_t)mat * TPT + ((size_t)rt * 64 + ty * 4) * 128 + ch * 64 + tx * 4;
  for (int i = 0; i < 4; ++i) {
    float4 v; v.x = acc[i][0]; v.y = acc[i][1]; v.z = acc[i][2]; v.w = acc[i][3];
    *(float4*)(dst + (size_t)i * 128) = v;
  }
}

// ------------------------------------------------------------------- decode
__global__ __launch_bounds__(1024, 4) void ptr1_decode_kernel(
    const float* __restrict__ enc, const float* __restrict__ mask0,
    const float* __restrict__ Wq1, const float* __restrict__ Wq3,
    const float* __restrict__ Wq4, const float* __restrict__ Wmh,
    const float* __restrict__ Wq2, const float* __restrict__ Vec2,
    const float* __restrict__ dec_inp, const float* __restrict__ proj,
    float* __restrict__ partials, int* __restrict__ flags,
    float* __restrict__ out) {
  const int g = blockIdx.x >> 4;   // batch / group
  const int c = blockIdx.x & 15;   // block within group
  const int tid = threadIdx.x;
  const int wv = tid >> 6;         // wave 0..15
  const int lane = tid & 63;
  const int half = lane >> 5;      // 32-lane half handles one row
  const int hl = lane & 31;
  const int h0 = hl << 2;          // 4 h-elems per lane
  const int start = c * ROWS;
  const int cnt = min(ROWS, Nn - start);   // 63, last block 55
  const int jrow = wv * 2 + half;          // 0..31 (always < cnt)
  const int j2 = jrow + 32;                // second row, guarded
  const bool a2 = j2 < cnt;
  const int j2c = a2 ? j2 : jrow;          // safe index for loads
  int* fl = flags + g * (16 * 32);

  __shared__ __align__(16) float hmean[128];
  __shared__ __align__(16) float qprev[128];
  __shared__ __align__(16) float qcur[128];
  __shared__ __align__(16) float base1[256];
  __shared__ __align__(16) float qm[2][128];
  __shared__ __align__(16) float gf[256];
  __shared__ __align__(16) float vecl[128];
  __shared__ __align__(16) float wpart[NW][2][132];
  __shared__ __align__(16) float qpart[4][256];
  __shared__ __align__(16) float mpart[8][128];
  __shared__ float spart[4][2];
  __shared__ float maskl[64];
  __shared__ float ulocal[64];
  __shared__ int sel_sh;
  __shared__ float logZ_sh;

  if (tid < 128) vecl[tid] = Vec2[tid];
  for (int j = tid; j < cnt; j += TPB) maskl[j] = mask0[(size_t)g * Nn + start + j];

  const size_t o1 = (size_t)jrow * Hh;
  const size_t o2 = (size_t)j2c * Hh;

  // ---- phase 0: h_mean, then base1 = hmean @ Wq1_top (once) ----
  {
    const float* eb = enc + ((size_t)g * Nn + start) * Hh + h0;
    const float4 eA = *(const float4*)(eb + o1);
    const float4 eB = *(const float4*)(eb + o2);
    float4 a;
    a.x = eA.x + (a2 ? eB.x : 0.f); a.y = eA.y + (a2 ? eB.y : 0.f);
    a.z = eA.z + (a2 ? eB.z : 0.f); a.w = eA.w + (a2 ? eB.w : 0.f);
    a.x += __shfl_xor(a.x, 32, 64); a.y += __shfl_xor(a.y, 32, 64);
    a.z += __shfl_xor(a.z, 32, 64); a.w += __shfl_xor(a.w, 32, 64);
    if (half == 0) *(float4*)&wpart[wv][0][4 + h0] = a;
    __syncthreads();
    if (tid < 128) {
      float s = 0.f;
      for (int w = 0; w < NW; ++w) s += wpart[w][0][4 + tid];
      astore(&partials[PPART(0, g, c, 0) + 4 + tid], s);
    }
    gbar(fl, c, 1, tid, lane);
    if (tid < 128) {
      float s = 0.f;
#pragma unroll 8
      for (int cc = 0; cc < NB; ++cc) s += aload(&partials[PPART(0, g, cc, 0) + 4 + tid]);
      hmean[tid] = s * (1.0f / (float)Nn);
    }
    if (tid >= 128 && tid < 256) qprev[tid - 128] = dec_inp[tid - 128];
    __syncthreads();
    {  // base1[m][h] = sum_{i<128} hmean[i] * Wq1[m][i][h]
      const int o = tid & 255, part = tid >> 8;
      const int m = o >> 7, h = o & 127;
      const float* wp = Wq1 + (size_t)m * 256 * 128 + (size_t)(part * 32) * 128 + h;
      const float* qc = hmean + part * 32;
      float acc = 0.f;
#pragma unroll 16
      for (int i = 0; i < 32; ++i) acc += qc[i] * wp[(size_t)i * 128];
      qpart[part][o] = acc;
    }
    __syncthreads();
    if (tid < 256)
      base1[tid] = qpart[0][tid] + qpart[1][tid] + qpart[2][tid] + qpart[3][tid];
    __syncthreads();
  }

  int p = 2;  // next barrier phase id (monotonic)
  for (int step = 0; step < Ss; ++step) {
    for (int gl = 0; gl < 3; ++gl) {
      const size_t rowb = ((size_t)g * Nn + start) * Hh + h0;
      const float* r0p = proj + (size_t)(4 * gl + 0) * TPT + rowb;
      const float* r1p = proj + (size_t)(4 * gl + 1) * TPT + rowb;
      const float* v0p = proj + (size_t)(4 * gl + 2) * TPT + rowb;
      const float* v1p = proj + (size_t)(4 * gl + 3) * TPT + rowb;
      // HOISTED streaming loads — independent of q, overlap the gemm below
      const float4 r0A = *(const float4*)(r0p + o1), r0B = *(const float4*)(r0p + o2);
      const float4 r1A = *(const float4*)(r1p + o1), r1B = *(const float4*)(r1p + o2);
      const float4 v0A = *(const float4*)(v0p + o1), v0B = *(const float4*)(v0p + o2);
      const float4 v1A = *(const float4*)(v1p + o1), v1B = *(const float4*)(v1p + o2);
      {  // q-proj: gl==0 -> base1 + qprev@Wq1_bot; else qcur@Wq (4-way split)
        const int o = tid & 255, part = tid >> 8;
        const int m = o >> 7, h = o & 127;
        const float* wp;
        const float* qc;
        if (gl == 0) {
          wp = Wq1 + (size_t)m * 256 * 128 + (size_t)(128 + part * 32) * 128 + h;
          qc = qprev + part * 32;
        } else {
          const float* Wq = (gl == 1) ? Wq3 : Wq4;
          wp = Wq + (size_t)m * 128 * 128 + (size_t)(part * 32) * 128 + h;
          qc = qcur + part * 32;
        }
        float acc = 0.f;
#pragma unroll 16
        for (int i = 0; i < 32; ++i) acc += qc[i] * wp[(size_t)i * 128];
        qpart[part][o] = acc;
      }
      __syncthreads();
      if (tid < 256) {
        float s = qpart[0][tid] + qpart[1][tid] + qpart[2][tid] + qpart[3][tid];
        if (gl == 0) s += base1[tid];
        (&qm[0][0])[tid] = s;
      }
      __syncthreads();

      const float4 qa = *(const float4*)&qm[0][h0];
      const float4 qb = *(const float4*)&qm[1][h0];
      const float mlA = maskl[jrow], mlB = maskl[j2c];
      float s0A = dot4t(qa, r0A, v0A), s1A = dot4t(qb, r1A, v1A);
      float s0B = dot4t(qa, r0B, v0B), s1B = dot4t(qb, r1B, v1B);
      red5_4(s0A, s1A, s0B, s1B);  // 32-lane row sums, 4 chains interleaved
      s0A = 10.f * tanh_fast(s0A) - 1e8f * mlA;
      s1A = 10.f * tanh_fast(s1A) - 1e8f * mlA;
      s0B = 10.f * tanh_fast(s0B) - 1e8f * mlB;
      s1B = 10.f * tanh_fast(s1B) - 1e8f * mlB;
      const float e0A = __expf(s0A - 10.f), e1A = __expf(s1A - 10.f);
      const float e0B = a2 ? __expf(s0B - 10.f) : 0.f;
      const float e1B = a2 ? __expf(s1B - 10.f) : 0.f;
      float S0 = e0A + e0B, S1 = e1A + e1B;
      float4 g0, g1;
      g0.x = e0A * r0A.x + e0B * r0B.x; g0.y = e0A * r0A.y + e0B * r0B.y;
      g0.z = e0A * r0A.z + e0B * r0B.z; g0.w = e0A * r0A.w + e0B * r0B.w;
      g1.x = e1A * r1A.x + e1B * r1B.x; g1.y = e1A * r1A.y + e1B * r1B.y;
      g1.z = e1A * r1A.z + e1B * r1B.z; g1.w = e1A * r1A.w + e1B * r1B.w;
      S0 += __shfl_xor(S0, 32, 64); S1 += __shfl_xor(S1, 32, 64);
      g0.x += __shfl_xor(g0.x, 32, 64); g0.y += __shfl_xor(g0.y, 32, 64);
      g0.z += __shfl_xor(g0.z, 32, 64); g0.w += __shfl_xor(g0.w, 32, 64);
      g1.x += __shfl_xor(g1.x, 32, 64); g1.y += __shfl_xor(g1.y, 32, 64);
      g1.z += __shfl_xor(g1.z, 32, 64); g1.w += __shfl_xor(g1.w, 32, 64);
      if (half == 0) {
        *(float4*)&wpart[wv][0][4 + h0] = g0;
        *(float4*)&wpart[wv][1][4 + h0] = g1;
        if (hl == 0) { wpart[wv][0][0] = S0; wpart[wv][1][0] = S1; }
      }
      __syncthreads();
      const int par = p & 1;
      if (tid < 256) {  // block combine -> global partial
        const int m = tid >> 7, h = tid & 127;
        float gs = 0.f;
        for (int w = 0; w < NW; ++w) gs += wpart[w][m][4 + h];
        float* gp = partials + PPART(par, g, c, m);
        astore(&gp[4 + h], gs);
        if (h == 0) {
          float ss = 0.f;
          for (int w = 0; w < NW; ++w) ss += wpart[w][m][0];
          astore(&gp[0], ss);
        }
      }
      gbar(fl, c, p, tid, lane);
      p++;
      {  // group combine, 4-way split over cc
        const int p4 = tid >> 8, o = tid & 255;
        const int m = o >> 7, h = o & 127;
        const int c0 = p4 * 4;
        float gx = 0.f;
#pragma unroll
        for (int cc = c0; cc < c0 + 4; ++cc)
          gx += aload(&partials[PPART(par, g, cc, m) + 4 + h]);
        qpart[p4][o] = gx;
        if (h == 0) {
          float Sx = 0.f;
#pragma unroll
          for (int cc = c0; cc < c0 + 4; ++cc)
            Sx += aload(&partials[PPART(par, g, cc, m)]);
          spart[p4][m] = Sx;
        }
      }
      __syncthreads();
      if (tid < 256) {
        const int m = tid >> 7;
        const float gx = qpart[0][tid] + qpart[1][tid] + qpart[2][tid] + qpart[3][tid];
        const float Sx = spart[0][m] + spart[1][m] + spart[2][m] + spart[3][m];
        gf[tid] = gx / Sx;  // softmax-weighted glimpse
      }
      __syncthreads();
      {  // merge heads: qnext = g_flat @ Wmh — 8-way split
        const int h = tid & 127, part = tid >> 7;
        float acc = 0.f;
        const float* wp = Wmh + (size_t)part * 32 * 128 + h;
        const float* gg = gf + part * 32;
#pragma unroll 16
        for (int i = 0; i < 32; ++i) acc += gg[i] * wp[(size_t)i * 128];
        mpart[part][h] = acc;
      }
      __syncthreads();
      if (tid < 128) {
        float acc = 0.f;
        for (int w = 0; w < 8; ++w) acc += mpart[w][tid];
        qcur[tid] = acc;
      }
      __syncthreads();
    }

    // ---- pointer ----
    const float* r2p = proj + (size_t)12 * TPT + ((size_t)g * Nn + start) * Hh + h0;
    const float4 rrA = *(const float4*)(r2p + o1);   // hoisted
    const float4 rrB = *(const float4*)(r2p + o2);
    {  // qptr = qcur @ Wq2 — 8-way split, seg 16
      const int h = tid & 127, part = tid >> 7;
      float acc = 0.f;
      const float* wp = Wq2 + (size_t)part * 16 * 128 + h;
      const float* qc = qcur + part * 16;
#pragma unroll
      for (int i = 0; i < 16; ++i) acc += qc[i] * wp[(size_t)i * 128];
      mpart[part][h] = acc;
    }
    __syncthreads();
    if (tid < 128) {
      float acc = 0.f;
      for (int w = 0; w < 8; ++w) acc += mpart[w][tid];
      qm[0][tid] = acc;
    }
    __syncthreads();
    {
      const float4 q2 = *(const float4*)&qm[0][h0];
      const float4 vz = *(const float4*)&vecl[h0];
      float upA = dot4t(q2, rrA, vz);
      float upB = dot4t(q2, rrB, vz);
      red5_2(upA, upB);
      const float mlA = maskl[jrow], mlB = maskl[j2c];
      const float uA = 10.f * tanh_fast(upA) - 1e8f * mlA;
      const float uB = a2 ? (10.f * tanh_fast(upB) - 1e8f * mlB) : -3.0e38f;
      if (hl == 0) {
        ulocal[jrow] = uA;
        if (a2) ulocal[j2] = uB;
      }
      float Sv = __expf(uA - 10.f) + (a2 ? __expf(uB - 10.f) : 0.f);
      float um = uA; int ui = start + jrow;
      if (a2 && uB > um) { um = uB; ui = start + j2; }
      Sv += __shfl_xor(Sv, 32, 64);
      const float um2 = __shfl_xor(um, 32, 64);
      const int ui2 = __shfl_xor(ui, 32, 64);
      if (um2 > um || (um2 == um && ui2 < ui)) { um = um2; ui = ui2; }
      if (lane == 0) {
        wpart[wv][0][0] = Sv; wpart[wv][0][1] = um;
        wpart[wv][0][2] = __int_as_float(ui);
      }
    }
    __syncthreads();
    const int par = p & 1;
    if (tid == 0) {
      float St = 0.f, bm = -3.0e38f; int bi = 0x7fffffff;
      for (int ww = 0; ww < NW; ++ww) {
        St += wpart[ww][0][0];
        const float m2 = wpart[ww][0][1];
        const int i2 = __float_as_int(wpart[ww][0][2]);
        if (m2 > bm || (m2 == bm && i2 < bi)) { bm = m2; bi = i2; }
      }
      float* gp = partials + PPART(par, g, c, 0);
      astore(&gp[0], St); astore(&gp[1], bm);
      astore(&gp[2], __int_as_float(bi));
    }
    gbar(fl, c, p, tid, lane);
    p++;
    if (tid < 64) {  // lane-parallel group argmax/logZ (one coherent RT)
      float St = 0.f, bm = -3.0e38f; int bi = 0x7fffffff;
      if (lane < NB) {
        const float* gp = partials + PPART(par, g, lane, 0);
        St = aload(&gp[0]); bm = aload(&gp[1]);
        bi = __float_as_int(aload(&gp[2]));
      }
#pragma unroll
      for (int m2 = 1; m2 <= 8; m2 <<= 1) {
        St += __shfl_xor(St, m2, 64);
        const float bm2 = __shfl_xor(bm, m2, 64);
        const int bi2 = __shfl_xor(bi, m2, 64);
        if (bm2 > bm || (bm2 == bm && bi2 < bi)) { bm = bm2; bi = bi2; }
      }
      if (lane == 0) { sel_sh = bi; logZ_sh = 10.f + __logf(St); }
    }
    __syncthreads();
    const int sel = sel_sh;
    const float lz = logZ_sh;
    if (tid < 128)  // prefetch selected row for next step's glimpse-1
      qprev[tid] = enc[((size_t)g * Nn + sel) * Hh + tid];
    for (int j = tid; j < cnt; j += TPB)
      out[(size_t)step * (Bb * Nn) + (size_t)g * Nn + start + j] = ulocal[j] - lz;
    if (c == 0 && tid == 0)
      out[(size_t)Ss * Bb * Nn + (size_t)step * Bb + g] = (float)sel;
    if (tid == 0 && sel >= start && sel < start + cnt) maskl[sel - start] = 1.0f;
    __syncthreads();
  }
}

// -------------------------------------------------------------------- launch
extern "C" void kernel_launch(void* const* d_in, const int* in_sizes, int n_in,
                              void* d_out, int out_size, void* d_ws, size_t ws_size,
                              hipStream_t stream) {
  const float* enc     = (const float*)d_in[0];
  const float* mask0   = (const float*)d_in[1];
  const float* Wq1     = (const float*)d_in[2];
  const float* Wref1   = (const float*)d_in[3];
  const float* Vec1    = (const float*)d_in[4];
  const float* Wq3     = (const float*)d_in[5];
  const float* Wref3   = (const float*)d_in[6];
  const float* Vec3    = (const float*)d_in[7];
  const float* Wq4     = (const float*)d_in[8];
  const float* Wref4   = (const float*)d_in[9];
  const float* Vec4    = (const float*)d_in[10];
  const float* Wmh     = (const float*)d_in[11];
  const float* Wq2     = (const float*)d_in[12];
  const float* Wref2   = (const float*)d_in[13];
  const float* Vec2    = (const float*)d_in[14];
  const float* dec_inp = (const float*)d_in[15];
  float* out = (float*)d_out;

  char* ws = (char*)d_ws;
  int* flags      = (int*)ws;                         // 16*16*32*4 = 32 KB
  float* partials = (float*)(ws + 32768);             // 540,672 B
  float* proj     = (float*)(ws + 32768 + 540672);    // 13 * 2,048,000 f32

  hipMemsetAsync(flags, 0, 32768, stream);

  dim3 pg(250, 26);
  ptr1_proj_kernel<<<pg, 256, 0, stream>>>(enc, Wref1, Vec1, Wref3, Vec3,
                                           Wref4, Vec4, Wref2, proj);

  void* args[] = {(void*)&enc,  (void*)&mask0, (void*)&Wq1, (void*)&Wq3,
                  (void*)&Wq4,  (void*)&Wmh,   (void*)&Wq2, (void*)&Vec2,
                  (void*)&dec_inp, (void*)&proj, (void*)&partials,
                  (void*)&flags, (void*)&out};
  hipLaunchCooperativeKernel((const void*)ptr1_decode_kernel, dim3(256),
                             dim3(1024), args, 0, stream);
}

// Round 6
// 1001.984 us; speedup vs baseline: 4.1329x; 1.2315x over previous
//
#include <hip/hip_runtime.h>

// PtrNet greedy decode, B=16, N=1000, H=128, M=2, 16 steps.
// Phase 1: proj_kernel — 13x [16000x128]@[128x128] f32 GEMM into ws.
// Phase 2: decode_kernel — persistent cooperative kernel, 16 groups x 16
//          blocks x 1024 threads. Flag-array barriers, atomicAdd-based
//          glimpse allreduce (1 coherent load fan-in instead of 16),
//          Wmh cached in LDS, nontemporal proj streaming (keeps Wq L2-hot).

#define Bb 16
#define Nn 1000
#define Hh 128
#define Ss 16
#define TPB 1024
#define NW 16                 // waves per block
#define NB 16                 // blocks per group
#define ROWS 63               // rows per block
#define TPT (Nn * Bb * Hh)    // elems per projection tensor slot: 2,048,000

// pointer-phase scalar slot: [par][g][c][m][132]
#define PPART(par, g, c, m) \
  ((((size_t)(par)*16 + (size_t)(g))*NB + (size_t)(c))*2 + (size_t)(m))*132
// glimpse accumulator: [buf][g][2][132] ; [0]=S, [4+h]=vector payload
#define ABUF(buf, g) (((size_t)(buf)*16 + (size_t)(g)) * 264)

typedef float f32x4 __attribute__((ext_vector_type(4)));
#define NTL(p) __builtin_nontemporal_load((const f32x4*)(p))

__device__ __forceinline__ void red5_2(float& a, float& b) {
#pragma unroll
  for (int m = 1; m <= 16; m <<= 1) {
    a += __shfl_xor(a, m, 64);
    b += __shfl_xor(b, m, 64);
  }
}
__device__ __forceinline__ void red5_4(float& a, float& b, float& c, float& d) {
#pragma unroll
  for (int m = 1; m <= 16; m <<= 1) {
    a += __shfl_xor(a, m, 64);
    b += __shfl_xor(b, m, 64);
    c += __shfl_xor(c, m, 64);
    d += __shfl_xor(d, m, 64);
  }
}

// fast tanh: (e-1)/(e+1), e=exp(2x), clamped so v_exp never overflows.
__device__ __forceinline__ float tanh_fast(float x) {
  const float xc = fminf(fmaxf(x, -10.f), 10.f);
  const float e = __expf(xc + xc);
  return (e - 1.f) * __builtin_amdgcn_rcpf(e + 1.f);
}
__device__ __forceinline__ float dot4t(const f32x4 q, const f32x4 r, const f32x4 v) {
  return tanh_fast(q[0] + r[0]) * v[0] + tanh_fast(q[1] + r[1]) * v[1] +
         tanh_fast(q[2] + r[2]) * v[2] + tanh_fast(q[3] + r[3]) * v[3];
}

// agent-coherent access (coherence point; bypasses stale L1/L2)
__device__ __forceinline__ float aload(const float* p) {
  return __hip_atomic_load(p, __ATOMIC_RELAXED, __HIP_MEMORY_SCOPE_AGENT);
}
__device__ __forceinline__ void astore(float* p, float v) {
  __hip_atomic_store(p, v, __ATOMIC_RELAXED, __HIP_MEMORY_SCOPE_AGENT);
}

// Flag-array group barrier: block c release-stores monotonic phase id to its
// own 128B-strided flag; wave 0 polls all NB flags in parallel.
__device__ __forceinline__ void gbar(int* fl, int c, int p, int tid, int lane) {
  __syncthreads();
  if (tid < 64) {
    if (lane == 0)
      __hip_atomic_store(&fl[c * 32], p, __ATOMIC_RELEASE, __HIP_MEMORY_SCOPE_AGENT);
    int v = p;
    while (true) {
      if (lane < NB)
        v = __hip_atomic_load(&fl[lane * 32], __ATOMIC_RELAXED, __HIP_MEMORY_SCOPE_AGENT);
      if (__all(v >= p)) break;
      __builtin_amdgcn_s_sleep(1);
    }
  }
  __syncthreads();
}

// ---------------------------------------------------------------- projections
__global__ __launch_bounds__(256) void ptr1_proj_kernel(
    const float* __restrict__ enc,
    const float* __restrict__ Wref1, const float* __restrict__ Vec1,
    const float* __restrict__ Wref3, const float* __restrict__ Vec3,
    const float* __restrict__ Wref4, const float* __restrict__ Vec4,
    const float* __restrict__ Wref2,
    float* __restrict__ outp) {
  __shared__ float At[128][64];  // A transposed [k][row]
  __shared__ float Bs[128][64];  // B [k][col-half]
  const int rt = blockIdx.x;     // 0..249 row tiles of 64
  const int wy = blockIdx.y;     // 0..25
  const int mat = wy >> 1;       // 0..12 output slot
  const int ch = wy & 1;         // column half
  const int tid = threadIdx.x;

  const float* W;
  switch (mat >> 1) {
    case 0: W = Wref1; break;
    case 1: W = Vec1;  break;
    case 2: W = Wref3; break;
    case 3: W = Vec3;  break;
    case 4: W = Wref4; break;
    case 5: W = Vec4;  break;
    default: W = Wref2; break;
  }
  if (mat < 12) W += (size_t)(mat & 1) * (128 * 128);

  const float* asrc = enc + (size_t)rt * 64 * 128;
  for (int f = tid; f < 64 * 32; f += 256) {
    const int r = f >> 5, k4 = (f & 31) << 2;
    const float4 v = *(const float4*)(asrc + (size_t)r * 128 + k4);
    At[k4 + 0][r] = v.x; At[k4 + 1][r] = v.y;
    At[k4 + 2][r] = v.z; At[k4 + 3][r] = v.w;
  }
  for (int f = tid; f < 128 * 16; f += 256) {
    const int k = f >> 4, c4 = (f & 15) << 2;
    *(float4*)&Bs[k][c4] = *(const float4*)(W + (size_t)k * 128 + ch * 64 + c4);
  }
  __syncthreads();

  const int tx = tid & 15, ty = tid >> 4;
  float acc[4][4] = {{0.f}};
  for (int k = 0; k < 128; ++k) {
    const float4 a = *(const float4*)&At[k][ty * 4];
    const float4 b = *(const float4*)&Bs[k][tx * 4];
    acc[0][0] += a.x * b.x; acc[0][1] += a.x * b.y; acc[0][2] += a.x * b.z; acc[0][3] += a.x * b.w;
    acc[1][0] += a.y * b.x; acc[1][1] += a.y * b.y; acc[1][2] += a.y * b.z; acc[1][3] += a.y * b.w;
    acc[2][0] += a.z * b.x; acc[2][1] += a.z * b.y; acc[2][2] += a.z * b.z; acc[2][3] += a.z * b.w;
    acc[3][0] += a.w * b.x; acc[3][1] += a.w * b.y; acc[3][2] += a.w * b.z; acc[3][3] += a.w * b.w;
  }
  float* dst = outp + (size_t)mat * TPT + ((size_t)rt * 64 + ty * 4) * 128 + ch * 64 + tx * 4;
  for (int i = 0; i < 4; ++i) {
    float4 v; v.x = acc[i][0]; v.y = acc[i][1]; v.z = acc[i][2]; v.w = acc[i][3];
    *(float4*)(dst + (size_t)i * 128) = v;
  }
}

// ------------------------------------------------------------------- decode
__global__ __launch_bounds__(1024, 4) void ptr1_decode_kernel(
    const float* __restrict__ enc, const float* __restrict__ mask0,
    const float* __restrict__ Wq1, const float* __restrict__ Wq3,
    const float* __restrict__ Wq4, const float* __restrict__ Wmh,
    const float* __restrict__ Wq2, const float* __restrict__ Vec2,
    const float* __restrict__ dec_inp, const float* __restrict__ proj,
    float* __restrict__ partials, float* __restrict__ accum,
    int* __restrict__ flags, float* __restrict__ out) {
  const int g = blockIdx.x >> 4;   // batch / group
  const int c = blockIdx.x & 15;   // block within group
  const int tid = threadIdx.x;
  const int wv = tid >> 6;         // wave 0..15
  const int lane = tid & 63;
  const int half = lane >> 5;      // 32-lane half handles one row
  const int hl = lane & 31;
  const int h0 = hl << 2;          // 4 h-elems per lane
  const int start = c * ROWS;
  const int cnt = min(ROWS, Nn - start);   // 63, last block 55
  const int jrow = wv * 2 + half;          // 0..31 (always < cnt)
  const int j2 = jrow + 32;                // second row, guarded
  const bool a2 = j2 < cnt;
  const int j2c = a2 ? j2 : jrow;          // safe index for loads
  int* fl = flags + g * (16 * 32);

  __shared__ float Wmh_lds[256 * 128];     // 131,072 B
  __shared__ __align__(16) float hmean[128];
  __shared__ __align__(16) float qprev[128];
  __shared__ __align__(16) float qcur[128];
  __shared__ __align__(16) float base1[256];
  __shared__ __align__(16) float qm[2][128];
  __shared__ __align__(16) float gfraw[256];
  __shared__ __align__(16) float vecl[128];
  __shared__ __align__(16) float wpart[NW][2][132];   // 16,896 B
  __shared__ __align__(16) float qpart[4][256];
  __shared__ __align__(16) float mpart[8][128];
  __shared__ float sS[2];
  __shared__ float maskl[64];
  __shared__ float ulocal[64];
  __shared__ int sel_sh;
  __shared__ float logZ_sh;

  // preload Wmh into LDS (coalesced float4), plus Vec2 and mask
  {
    float4* wl = (float4*)Wmh_lds;
    const float4* wg = (const float4*)Wmh;
#pragma unroll
    for (int k = 0; k < 8; ++k) wl[tid + k * TPB] = wg[tid + k * TPB];
  }
  if (tid < 128) vecl[tid] = Vec2[tid];
  for (int j = tid; j < cnt; j += TPB) maskl[j] = mask0[(size_t)g * Nn + start + j];

  const size_t o1 = (size_t)jrow * Hh;
  const size_t o2 = (size_t)j2c * Hh;

  // ---- phase 0: h_mean, then base1 = hmean @ Wq1_top (once) ----
  {
    const float* eb = enc + ((size_t)g * Nn + start) * Hh + h0;
    const float4 eA = *(const float4*)(eb + o1);
    const float4 eB = *(const float4*)(eb + o2);
    float4 a;
    a.x = eA.x + (a2 ? eB.x : 0.f); a.y = eA.y + (a2 ? eB.y : 0.f);
    a.z = eA.z + (a2 ? eB.z : 0.f); a.w = eA.w + (a2 ? eB.w : 0.f);
    a.x += __shfl_xor(a.x, 32, 64); a.y += __shfl_xor(a.y, 32, 64);
    a.z += __shfl_xor(a.z, 32, 64); a.w += __shfl_xor(a.w, 32, 64);
    if (half == 0) *(float4*)&wpart[wv][0][4 + h0] = a;
    __syncthreads();
    if (tid < 128) {
      float s = 0.f;
      for (int w = 0; w < NW; ++w) s += wpart[w][0][4 + tid];
      astore(&partials[PPART(0, g, c, 0) + 4 + tid], s);
    }
    gbar(fl, c, 1, tid, lane);
    if (tid < 128) {
      float s = 0.f;
#pragma unroll 8
      for (int cc = 0; cc < NB; ++cc) s += aload(&partials[PPART(0, g, cc, 0) + 4 + tid]);
      hmean[tid] = s * (1.0f / (float)Nn);
    }
    if (tid >= 128 && tid < 256) qprev[tid - 128] = dec_inp[tid - 128];
    __syncthreads();
    {  // base1[m][h] = sum_{i<128} hmean[i] * Wq1[m][i][h]
      const int o = tid & 255, part = tid >> 8;
      const int m = o >> 7, h = o & 127;
      const float* wp = Wq1 + (size_t)m * 256 * 128 + (size_t)(part * 32) * 128 + h;
      const float* qc = hmean + part * 32;
      float acc = 0.f;
#pragma unroll 16
      for (int i = 0; i < 32; ++i) acc += qc[i] * wp[(size_t)i * 128];
      qpart[part][o] = acc;
    }
    __syncthreads();
    if (tid < 256)
      base1[tid] = qpart[0][tid] + qpart[1][tid] + qpart[2][tid] + qpart[3][tid];
    __syncthreads();
  }

  int p = 2;  // next barrier phase id (monotonic)
  for (int step = 0; step < Ss; ++step) {
    for (int gl = 0; gl < 3; ++gl) {
      const size_t rowb = ((size_t)g * Nn + start) * Hh + h0;
      const float* r0p = proj + (size_t)(4 * gl + 0) * TPT + rowb;
      const float* r1p = proj + (size_t)(4 * gl + 1) * TPT + rowb;
      const float* v0p = proj + (size_t)(4 * gl + 2) * TPT + rowb;
      const float* v1p = proj + (size_t)(4 * gl + 3) * TPT + rowb;
      // HOISTED nontemporal streaming loads — overlap the gemm below,
      // bypass L2 so Wq/Wq2 weights stay L2-resident.
      const f32x4 r0A = NTL(r0p + o1), r0B = NTL(r0p + o2);
      const f32x4 r1A = NTL(r1p + o1), r1B = NTL(r1p + o2);
      const f32x4 v0A = NTL(v0p + o1), v0B = NTL(v0p + o2);
      const f32x4 v1A = NTL(v1p + o1), v1B = NTL(v1p + o2);
      {  // q-proj: gl==0 -> base1 + qprev@Wq1_bot; else qcur@Wq (4-way split)
        const int o = tid & 255, part = tid >> 8;
        const int m = o >> 7, h = o & 127;
        const float* wp;
        const float* qc;
        if (gl == 0) {
          wp = Wq1 + (size_t)m * 256 * 128 + (size_t)(128 + part * 32) * 128 + h;
          qc = qprev + part * 32;
        } else {
          const float* Wq = (gl == 1) ? Wq3 : Wq4;
          wp = Wq + (size_t)m * 128 * 128 + (size_t)(part * 32) * 128 + h;
          qc = qcur + part * 32;
        }
        float acc = 0.f;
#pragma unroll 16
        for (int i = 0; i < 32; ++i) acc += qc[i] * wp[(size_t)i * 128];
        qpart[part][o] = acc;
      }
      __syncthreads();
      if (tid < 256) {
        float s = qpart[0][tid] + qpart[1][tid] + qpart[2][tid] + qpart[3][tid];
        if (gl == 0) s += base1[tid];
        (&qm[0][0])[tid] = s;
      }
      __syncthreads();

      const f32x4 qa = *(const f32x4*)&qm[0][h0];
      const f32x4 qb = *(const f32x4*)&qm[1][h0];
      const float mlA = maskl[jrow], mlB = maskl[j2c];
      float s0A = dot4t(qa, r0A, v0A), s1A = dot4t(qb, r1A, v1A);
      float s0B = dot4t(qa, r0B, v0B), s1B = dot4t(qb, r1B, v1B);
      red5_4(s0A, s1A, s0B, s1B);  // 32-lane row sums, 4 chains interleaved
      s0A = 10.f * tanh_fast(s0A) - 1e8f * mlA;
      s1A = 10.f * tanh_fast(s1A) - 1e8f * mlA;
      s0B = 10.f * tanh_fast(s0B) - 1e8f * mlB;
      s1B = 10.f * tanh_fast(s1B) - 1e8f * mlB;
      const float e0A = __expf(s0A - 10.f), e1A = __expf(s1A - 10.f);
      const float e0B = a2 ? __expf(s0B - 10.f) : 0.f;
      const float e1B = a2 ? __expf(s1B - 10.f) : 0.f;
      float S0 = e0A + e0B, S1 = e1A + e1B;
      float4 g0, g1;
      g0.x = e0A * r0A[0] + e0B * r0B[0]; g0.y = e0A * r0A[1] + e0B * r0B[1];
      g0.z = e0A * r0A[2] + e0B * r0B[2]; g0.w = e0A * r0A[3] + e0B * r0B[3];
      g1.x = e1A * r1A[0] + e1B * r1B[0]; g1.y = e1A * r1A[1] + e1B * r1B[1];
      g1.z = e1A * r1A[2] + e1B * r1B[2]; g1.w = e1A * r1A[3] + e1B * r1B[3];
      S0 += __shfl_xor(S0, 32, 64); S1 += __shfl_xor(S1, 32, 64);
      g0.x += __shfl_xor(g0.x, 32, 64); g0.y += __shfl_xor(g0.y, 32, 64);
      g0.z += __shfl_xor(g0.z, 32, 64); g0.w += __shfl_xor(g0.w, 32, 64);
      g1.x += __shfl_xor(g1.x, 32, 64); g1.y += __shfl_xor(g1.y, 32, 64);
      g1.z += __shfl_xor(g1.z, 32, 64); g1.w += __shfl_xor(g1.w, 32, 64);
      if (half == 0) {
        *(float4*)&wpart[wv][0][4 + h0] = g0;
        *(float4*)&wpart[wv][1][4 + h0] = g1;
        if (hl == 0) { wpart[wv][0][0] = S0; wpart[wv][1][0] = S1; }
      }
      __syncthreads();
      float* ab = accum + ABUF(p & 3, g);
      float* zb = accum + ABUF((p + 1) & 3, g);
      if (tid < 256) {  // block combine -> atomic accumulate at coherence pt
        const int m = tid >> 7, h = tid & 127;
        float gs = 0.f;
        for (int w = 0; w < NW; ++w) gs += wpart[w][m][4 + h];
        unsafeAtomicAdd(&ab[m * 132 + 4 + h], gs);
        if (h == 0) {
          float ss = 0.f;
          for (int w = 0; w < NW; ++w) ss += wpart[w][m][0];
          unsafeAtomicAdd(&ab[m * 132], ss);
        }
      } else if (tid >= 512 && tid < 512 + 17) {  // zero next phase's buffer
        const int idx = c * 17 + (tid - 512);
        if (idx < 264) astore(&zb[idx], 0.f);
      }
      gbar(fl, c, p, tid, lane);
      p++;
      // group read: ONE coherent load per thread (sum already formed)
      if (tid < 256) gfraw[tid] = aload(&ab[(tid >> 7) * 132 + 4 + (tid & 127)]);
      if (tid >= 256 && tid < 258) sS[tid - 256] = aload(&ab[(tid - 256) * 132]);
      __syncthreads();
      {  // merge heads from LDS Wmh, divide folded in: q = (gx @ Wmh)/S
        const int h = tid & 127, part = tid >> 7;
        const int m = part >> 2;
        float acc = 0.f;
        const float* wl = Wmh_lds + (size_t)part * 32 * 128 + h;
        const float* gg = gfraw + part * 32;
#pragma unroll 16
        for (int i = 0; i < 32; ++i) acc += gg[i] * wl[i * 128];
        mpart[part][h] = acc / sS[m];
      }
      __syncthreads();
      if (tid < 128) {
        float acc = 0.f;
        for (int w = 0; w < 8; ++w) acc += mpart[w][tid];
        qcur[tid] = acc;
      }
      __syncthreads();
    }

    // ---- pointer ----
    const float* r2p = proj + (size_t)12 * TPT + ((size_t)g * Nn + start) * Hh + h0;
    const f32x4 rrA = NTL(r2p + o1);   // hoisted
    const f32x4 rrB = NTL(r2p + o2);
    {  // qptr = qcur @ Wq2 — 8-way split, seg 16
      const int h = tid & 127, part = tid >> 7;
      float acc = 0.f;
      const float* wp = Wq2 + (size_t)part * 16 * 128 + h;
      const float* qc = qcur + part * 16;
#pragma unroll
      for (int i = 0; i < 16; ++i) acc += qc[i] * wp[(size_t)i * 128];
      mpart[part][h] = acc;
    }
    __syncthreads();
    if (tid < 128) {
      float acc = 0.f;
      for (int w = 0; w < 8; ++w) acc += mpart[w][tid];
      qm[0][tid] = acc;
    }
    __syncthreads();
    {
      const f32x4 q2 = *(const f32x4*)&qm[0][h0];
      const f32x4 vz = *(const f32x4*)&vecl[h0];
      float upA = dot4t(q2, rrA, vz);
      float upB = dot4t(q2, rrB, vz);
      red5_2(upA, upB);
      const float mlA = maskl[jrow], mlB = maskl[j2c];
      const float uA = 10.f * tanh_fast(upA) - 1e8f * mlA;
      const float uB = a2 ? (10.f * tanh_fast(upB) - 1e8f * mlB) : -3.0e38f;
      if (hl == 0) {
        ulocal[jrow] = uA;
        if (a2) ulocal[j2] = uB;
      }
      float Sv = __expf(uA - 10.f) + (a2 ? __expf(uB - 10.f) : 0.f);
      float um = uA; int ui = start + jrow;
      if (a2 && uB > um) { um = uB; ui = start + j2; }
      Sv += __shfl_xor(Sv, 32, 64);
      const float um2 = __shfl_xor(um, 32, 64);
      const int ui2 = __shfl_xor(ui, 32, 64);
      if (um2 > um || (um2 == um && ui2 < ui)) { um = um2; ui = ui2; }
      if (lane == 0) {
        wpart[wv][0][0] = Sv; wpart[wv][0][1] = um;
        wpart[wv][0][2] = __int_as_float(ui);
      }
    }
    __syncthreads();
    const int par = p & 1;
    if (tid == 0) {
      float St = 0.f, bm = -3.0e38f; int bi = 0x7fffffff;
      for (int ww = 0; ww < NW; ++ww) {
        St += wpart[ww][0][0];
        const float m2 = wpart[ww][0][1];
        const int i2 = __float_as_int(wpart[ww][0][2]);
        if (m2 > bm || (m2 == bm && i2 < bi)) { bm = m2; bi = i2; }
      }
      float* gp = partials + PPART(par, g, c, 0);
      astore(&gp[0], St); astore(&gp[1], bm);
      astore(&gp[2], __int_as_float(bi));
    } else if (tid >= 512 && tid < 512 + 17) {  // zero next phase's accum buf
      float* zb = accum + ABUF((p + 1) & 3, g);
      const int idx = c * 17 + (tid - 512);
      if (idx < 264) astore(&zb[idx], 0.f);
    }
    gbar(fl, c, p, tid, lane);
    p++;
    if (tid < 64) {  // lane-parallel group argmax/logZ (one coherent RT)
      float St = 0.f, bm = -3.0e38f; int bi = 0x7fffffff;
      if (lane < NB) {
        const float* gp = partials + PPART(par, g, lane, 0);
        St = aload(&gp[0]); bm = aload(&gp[1]);
        bi = __float_as_int(aload(&gp[2]));
      }
#pragma unroll
      for (int m2 = 1; m2 <= 8; m2 <<= 1) {
        St += __shfl_xor(St, m2, 64);
        const float bm2 = __shfl_xor(bm, m2, 64);
        const int bi2 = __shfl_xor(bi, m2, 64);
        if (bm2 > bm || (bm2 == bm && bi2 < bi)) { bm = bm2; bi = bi2; }
      }
      if (lane == 0) { sel_sh = bi; logZ_sh = 10.f + __logf(St); }
    }
    __syncthreads();
    const int sel = sel_sh;
    const float lz = logZ_sh;
    if (tid < 128)  // prefetch selected row for next step's glimpse-1
      qprev[tid] = enc[((size_t)g * Nn + sel) * Hh + tid];
    for (int j = tid; j < cnt; j += TPB)
      out[(size_t)step * (Bb * Nn) + (size_t)g * Nn + start + j] = ulocal[j] - lz;
    if (c == 0 && tid == 0)
      out[(size_t)Ss * Bb * Nn + (size_t)step * Bb + g] = (float)sel;
    if (tid == 0 && sel >= start && sel < start + cnt) maskl[sel - start] = 1.0f;
    __syncthreads();
  }
}

// -------------------------------------------------------------------- launch
extern "C" void kernel_launch(void* const* d_in, const int* in_sizes, int n_in,
                              void* d_out, int out_size, void* d_ws, size_t ws_size,
                              hipStream_t stream) {
  const float* enc     = (const float*)d_in[0];
  const float* mask0   = (const float*)d_in[1];
  const float* Wq1     = (const float*)d_in[2];
  const float* Wref1   = (const float*)d_in[3];
  const float* Vec1    = (const float*)d_in[4];
  const float* Wq3     = (const float*)d_in[5];
  const float* Wref3   = (const float*)d_in[6];
  const float* Vec3    = (const float*)d_in[7];
  const float* Wq4     = (const float*)d_in[8];
  const float* Wref4   = (const float*)d_in[9];
  const float* Vec4    = (const float*)d_in[10];
  const float* Wmh     = (const float*)d_in[11];
  const float* Wq2     = (const float*)d_in[12];
  const float* Wref2   = (const float*)d_in[13];
  const float* Vec2    = (const float*)d_in[14];
  const float* dec_inp = (const float*)d_in[15];
  float* out = (float*)d_out;

  char* ws = (char*)d_ws;
  int* flags      = (int*)ws;                          // 32 KB
  float* accum    = (float*)(ws + 32768);              // 4*16*264*4 = 67,584 B
  float* partials = (float*)(ws + 102400);             // 540,672 B
  float* proj     = (float*)(ws + 102400 + 540672);    // 13 * 2,048,000 f32

  hipMemsetAsync(ws, 0, 102400, stream);  // zero flags + accum buffers

  dim3 pg(250, 26);
  ptr1_proj_kernel<<<pg, 256, 0, stream>>>(enc, Wref1, Vec1, Wref3, Vec3,
                                           Wref4, Vec4, Wref2, proj);

  void* args[] = {(void*)&enc,  (void*)&mask0, (void*)&Wq1, (void*)&Wq3,
                  (void*)&Wq4,  (void*)&Wmh,   (void*)&Wq2, (void*)&Vec2,
                  (void*)&dec_inp, (void*)&proj, (void*)&partials,
                  (void*)&accum, (void*)&flags, (void*)&out};
  hipLaunchCooperativeKernel((const void*)ptr1_decode_kernel, dim3(256),
                             dim3(1024), args, 0, stream);
}

// Round 7
// 988.111 us; speedup vs baseline: 4.1910x; 1.0140x over previous
//
#include <hip/hip_runtime.h>

// PtrNet greedy decode, B=16, N=1000, H=128, M=2, 16 steps.
// Phase 1: proj_kernel — 13x [16000x128]@[128x128] f32 GEMM into ws.
// Phase 2: decode_kernel — persistent cooperative kernel, 16 groups x 16
//          blocks x 1024 threads. Flag-array barriers (pure spin),
//          atomicAdd glimpse allreduce, fused atomicMax pointer argmax,
//          Wmh in LDS, nontemporal proj streaming with sched_barrier-pinned
//          hoisted loads (anti-sink).

#define Bb 16
#define Nn 1000
#define Hh 128
#define Ss 16
#define TPB 1024
#define NW 16                 // waves per block
#define NB 16                 // blocks per group
#define ROWS 63               // rows per block
#define TPT (Nn * Bb * Hh)    // elems per projection tensor slot: 2,048,000

// hmean-phase slot: [par][g][c][m][132]
#define PPART(par, g, c, m) \
  ((((size_t)(par)*16 + (size_t)(g))*NB + (size_t)(c))*2 + (size_t)(m))*132
// allreduce accumulator: [buf][g][272]:
//   [0]=S0 [4..131]=vec0 ; [132]=S1 [136..263]=vec1 ; [264..265]=u64 argmax key
#define ABUF(buf, g) (((size_t)(buf)*16 + (size_t)(g)) * 272)

typedef float f32x4 __attribute__((ext_vector_type(4)));
#define NTL(p) __builtin_nontemporal_load((const f32x4*)(p))

__device__ __forceinline__ void red5_2(float& a, float& b) {
#pragma unroll
  for (int m = 1; m <= 16; m <<= 1) {
    a += __shfl_xor(a, m, 64);
    b += __shfl_xor(b, m, 64);
  }
}
__device__ __forceinline__ void red5_4(float& a, float& b, float& c, float& d) {
#pragma unroll
  for (int m = 1; m <= 16; m <<= 1) {
    a += __shfl_xor(a, m, 64);
    b += __shfl_xor(b, m, 64);
    c += __shfl_xor(c, m, 64);
    d += __shfl_xor(d, m, 64);
  }
}

// fast tanh: (e-1)/(e+1), e=exp(2x), clamped so v_exp never overflows.
__device__ __forceinline__ float tanh_fast(float x) {
  const float xc = fminf(fmaxf(x, -10.f), 10.f);
  const float e = __expf(xc + xc);
  return (e - 1.f) * __builtin_amdgcn_rcpf(e + 1.f);
}
__device__ __forceinline__ float dot4t(const f32x4 q, const f32x4 r, const f32x4 v) {
  return tanh_fast(q[0] + r[0]) * v[0] + tanh_fast(q[1] + r[1]) * v[1] +
         tanh_fast(q[2] + r[2]) * v[2] + tanh_fast(q[3] + r[3]) * v[3];
}

// agent-coherent access (coherence point; bypasses stale L1/L2)
__device__ __forceinline__ float aload(const float* p) {
  return __hip_atomic_load(p, __ATOMIC_RELAXED, __HIP_MEMORY_SCOPE_AGENT);
}
__device__ __forceinline__ void astore(float* p, float v) {
  __hip_atomic_store(p, v, __ATOMIC_RELAXED, __HIP_MEMORY_SCOPE_AGENT);
}

// Flag-array group barrier: block c release-stores monotonic phase id to its
// own 128B-strided flag; wave 0 spins on all NB flags in parallel.
__device__ __forceinline__ void gbar(int* fl, int c, int p, int tid, int lane) {
  __syncthreads();
  if (tid < 64) {
    if (lane == 0)
      __hip_atomic_store(&fl[c * 32], p, __ATOMIC_RELEASE, __HIP_MEMORY_SCOPE_AGENT);
    int v = p;
    while (true) {
      if (lane < NB)
        v = __hip_atomic_load(&fl[lane * 32], __ATOMIC_RELAXED, __HIP_MEMORY_SCOPE_AGENT);
      if (__all(v >= p)) break;
    }
  }
  __syncthreads();
}

// ---------------------------------------------------------------- projections
__global__ __launch_bounds__(256) void ptr1_proj_kernel(
    const float* __restrict__ enc,
    const float* __restrict__ Wref1, const float* __restrict__ Vec1,
    const float* __restrict__ Wref3, const float* __restrict__ Vec3,
    const float* __restrict__ Wref4, const float* __restrict__ Vec4,
    const float* __restrict__ Wref2,
    float* __restrict__ outp) {
  __shared__ float At[128][64];  // A transposed [k][row]
  __shared__ float Bs[128][64];  // B [k][col-half]
  const int rt = blockIdx.x;     // 0..249 row tiles of 64
  const int wy = blockIdx.y;     // 0..25
  const int mat = wy >> 1;       // 0..12 output slot
  const int ch = wy & 1;         // column half
  const int tid = threadIdx.x;

  const float* W;
  switch (mat >> 1) {
    case 0: W = Wref1; break;
    case 1: W = Vec1;  break;
    case 2: W = Wref3; break;
    case 3: W = Vec3;  break;
    case 4: W = Wref4; break;
    case 5: W = Vec4;  break;
    default: W = Wref2; break;
  }
  if (mat < 12) W += (size_t)(mat & 1) * (128 * 128);

  const float* asrc = enc + (size_t)rt * 64 * 128;
  for (int f = tid; f < 64 * 32; f += 256) {
    const int r = f >> 5, k4 = (f & 31) << 2;
    const float4 v = *(const float4*)(asrc + (size_t)r * 128 + k4);
    At[k4 + 0][r] = v.x; At[k4 + 1][r] = v.y;
    At[k4 + 2][r] = v.z; At[k4 + 3][r] = v.w;
  }
  for (int f = tid; f < 128 * 16; f += 256) {
    const int k = f >> 4, c4 = (f & 15) << 2;
    *(float4*)&Bs[k][c4] = *(const float4*)(W + (size_t)k * 128 + ch * 64 + c4);
  }
  __syncthreads();

  const int tx = tid & 15, ty = tid >> 4;
  float acc[4][4] = {{0.f}};
  for (int k = 0; k < 128; ++k) {
    const float4 a = *(const float4*)&At[k][ty * 4];
    const float4 b = *(const float4*)&Bs[k][tx * 4];
    acc[0][0] += a.x * b.x; acc[0][1] += a.x * b.y; acc[0][2] += a.x * b.z; acc[0][3] += a.x * b.w;
    acc[1][0] += a.y * b.x; acc[1][1] += a.y * b.y; acc[1][2] += a.y * b.z; acc[1][3] += a.y * b.w;
    acc[2][0] += a.z * b.x; acc[2][1] += a.z * b.y; acc[2][2] += a.z * b.z; acc[2][3] += a.z * b.w;
    acc[3][0] += a.w * b.x; acc[3][1] += a.w * b.y; acc[3][2] += a.w * b.z; acc[3][3] += a.w * b.w;
  }
  float* dst = outp + (size_t)mat * TPT + ((size_t)rt * 64 + ty * 4) * 128 + ch * 64 + tx * 4;
  for (int i = 0; i < 4; ++i) {
    float4 v; v.x = acc[i][0]; v.y = acc[i][1]; v.z = acc[i][2]; v.w = acc[i][3];
    *(float4*)(dst + (size_t)i * 128) = v;
  }
}

// ------------------------------------------------------------------- decode
__global__ __launch_bounds__(1024, 4) void ptr1_decode_kernel(
    const float* __restrict__ enc, const float* __restrict__ mask0,
    const float* __restrict__ Wq1, const float* __restrict__ Wq3,
    const float* __restrict__ Wq4, const float* __restrict__ Wmh,
    const float* __restrict__ Wq2, const float* __restrict__ Vec2,
    const float* __restrict__ dec_inp, const float* __restrict__ proj,
    float* __restrict__ partials, float* __restrict__ accum,
    int* __restrict__ flags, float* __restrict__ out) {
  const int g = blockIdx.x >> 4;   // batch / group
  const int c = blockIdx.x & 15;   // block within group
  const int tid = threadIdx.x;
  const int wv = tid >> 6;         // wave 0..15
  const int lane = tid & 63;
  const int half = lane >> 5;      // 32-lane half handles one row
  const int hl = lane & 31;
  const int h0 = hl << 2;          // 4 h-elems per lane
  const int start = c * ROWS;
  const int cnt = min(ROWS, Nn - start);   // 63, last block 55
  const int jrow = wv * 2 + half;          // 0..31 (always < cnt)
  const int j2 = jrow + 32;                // second row, guarded
  const bool a2 = j2 < cnt;
  const int j2c = a2 ? j2 : jrow;          // safe index for loads
  int* fl = flags + g * (16 * 32);

  __shared__ float Wmh_lds[256 * 128];     // 131,072 B
  __shared__ __align__(16) float hmean[128];
  __shared__ __align__(16) float qprev[128];
  __shared__ __align__(16) float qcur[128];
  __shared__ __align__(16) float base1[256];
  __shared__ __align__(16) float qm[2][128];
  __shared__ __align__(16) float gfraw[256];
  __shared__ __align__(16) float vecl[128];
  __shared__ __align__(16) float wpart[NW][2][132];   // 16,896 B
  __shared__ __align__(16) float qpart[4][256];
  __shared__ __align__(16) float mpart[8][128];
  __shared__ float sS[2];
  __shared__ float maskl[64];
  __shared__ float ulocal[64];
  __shared__ int sel_sh;
  __shared__ float logZ_sh;

  // preload Wmh into LDS (coalesced float4), plus Vec2 and mask
  {
    float4* wl = (float4*)Wmh_lds;
    const float4* wg = (const float4*)Wmh;
#pragma unroll
    for (int k = 0; k < 8; ++k) wl[tid + k * TPB] = wg[tid + k * TPB];
  }
  if (tid < 128) vecl[tid] = Vec2[tid];
  for (int j = tid; j < cnt; j += TPB) maskl[j] = mask0[(size_t)g * Nn + start + j];

  const size_t o1 = (size_t)jrow * Hh;
  const size_t o2 = (size_t)j2c * Hh;

  // ---- phase 0: h_mean, then base1 = hmean @ Wq1_top (once) ----
  {
    const float* eb = enc + ((size_t)g * Nn + start) * Hh + h0;
    const float4 eA = *(const float4*)(eb + o1);
    const float4 eB = *(const float4*)(eb + o2);
    float4 a;
    a.x = eA.x + (a2 ? eB.x : 0.f); a.y = eA.y + (a2 ? eB.y : 0.f);
    a.z = eA.z + (a2 ? eB.z : 0.f); a.w = eA.w + (a2 ? eB.w : 0.f);
    a.x += __shfl_xor(a.x, 32, 64); a.y += __shfl_xor(a.y, 32, 64);
    a.z += __shfl_xor(a.z, 32, 64); a.w += __shfl_xor(a.w, 32, 64);
    if (half == 0) *(float4*)&wpart[wv][0][4 + h0] = a;
    __syncthreads();
    if (tid < 128) {
      float s = 0.f;
      for (int w = 0; w < NW; ++w) s += wpart[w][0][4 + tid];
      astore(&partials[PPART(0, g, c, 0) + 4 + tid], s);
    }
    gbar(fl, c, 1, tid, lane);
    if (tid < 128) {
      float s = 0.f;
#pragma unroll 8
      for (int cc = 0; cc < NB; ++cc) s += aload(&partials[PPART(0, g, cc, 0) + 4 + tid]);
      hmean[tid] = s * (1.0f / (float)Nn);
    }
    if (tid >= 128 && tid < 256) qprev[tid - 128] = dec_inp[tid - 128];
    __syncthreads();
    {  // base1[m][h] = sum_{i<128} hmean[i] * Wq1[m][i][h]
      const int o = tid & 255, part = tid >> 8;
      const int m = o >> 7, h = o & 127;
      const float* wp = Wq1 + (size_t)m * 256 * 128 + (size_t)(part * 32) * 128 + h;
      const float* qc = hmean + part * 32;
      float acc = 0.f;
#pragma unroll 16
      for (int i = 0; i < 32; ++i) acc += qc[i] * wp[(size_t)i * 128];
      qpart[part][o] = acc;
    }
    __syncthreads();
    if (tid < 256)
      base1[tid] = qpart[0][tid] + qpart[1][tid] + qpart[2][tid] + qpart[3][tid];
    __syncthreads();
  }

  int p = 2;  // next barrier phase id (monotonic)
  for (int step = 0; step < Ss; ++step) {
    for (int gl = 0; gl < 3; ++gl) {
      const size_t rowb = ((size_t)g * Nn + start) * Hh + h0;
      const float* r0p = proj + (size_t)(4 * gl + 0) * TPT + rowb;
      const float* r1p = proj + (size_t)(4 * gl + 1) * TPT + rowb;
      const float* v0p = proj + (size_t)(4 * gl + 2) * TPT + rowb;
      const float* v1p = proj + (size_t)(4 * gl + 3) * TPT + rowb;
      // HOISTED nontemporal streaming loads, pinned above the gemm (anti-sink)
      const f32x4 r0A = NTL(r0p + o1), r0B = NTL(r0p + o2);
      const f32x4 r1A = NTL(r1p + o1), r1B = NTL(r1p + o2);
      const f32x4 v0A = NTL(v0p + o1), v0B = NTL(v0p + o2);
      const f32x4 v1A = NTL(v1p + o1), v1B = NTL(v1p + o2);
      __builtin_amdgcn_sched_barrier(0);
      {  // q-proj: gl==0 -> base1 + qprev@Wq1_bot; else qcur@Wq (4-way split)
        const int o = tid & 255, part = tid >> 8;
        const int m = o >> 7, h = o & 127;
        const float* wp;
        const float* qc;
        if (gl == 0) {
          wp = Wq1 + (size_t)m * 256 * 128 + (size_t)(128 + part * 32) * 128 + h;
          qc = qprev + part * 32;
        } else {
          const float* Wq = (gl == 1) ? Wq3 : Wq4;
          wp = Wq + (size_t)m * 128 * 128 + (size_t)(part * 32) * 128 + h;
          qc = qcur + part * 32;
        }
        float acc = 0.f;
#pragma unroll 16
        for (int i = 0; i < 32; ++i) acc += qc[i] * wp[(size_t)i * 128];
        qpart[part][o] = acc;
      }
      __syncthreads();
      if (tid < 256) {
        float s = qpart[0][tid] + qpart[1][tid] + qpart[2][tid] + qpart[3][tid];
        if (gl == 0) s += base1[tid];
        (&qm[0][0])[tid] = s;
      }
      __syncthreads();

      const f32x4 qa = *(const f32x4*)&qm[0][h0];
      const f32x4 qb = *(const f32x4*)&qm[1][h0];
      const float mlA = maskl[jrow], mlB = maskl[j2c];
      float s0A = dot4t(qa, r0A, v0A), s1A = dot4t(qb, r1A, v1A);
      float s0B = dot4t(qa, r0B, v0B), s1B = dot4t(qb, r1B, v1B);
      red5_4(s0A, s1A, s0B, s1B);  // 32-lane row sums, 4 chains interleaved
      s0A = 10.f * tanh_fast(s0A) - 1e8f * mlA;
      s1A = 10.f * tanh_fast(s1A) - 1e8f * mlA;
      s0B = 10.f * tanh_fast(s0B) - 1e8f * mlB;
      s1B = 10.f * tanh_fast(s1B) - 1e8f * mlB;
      const float e0A = __expf(s0A - 10.f), e1A = __expf(s1A - 10.f);
      const float e0B = a2 ? __expf(s0B - 10.f) : 0.f;
      const float e1B = a2 ? __expf(s1B - 10.f) : 0.f;
      float S0 = e0A + e0B, S1 = e1A + e1B;
      float4 g0, g1;
      g0.x = e0A * r0A[0] + e0B * r0B[0]; g0.y = e0A * r0A[1] + e0B * r0B[1];
      g0.z = e0A * r0A[2] + e0B * r0B[2]; g0.w = e0A * r0A[3] + e0B * r0B[3];
      g1.x = e1A * r1A[0] + e1B * r1B[0]; g1.y = e1A * r1A[1] + e1B * r1B[1];
      g1.z = e1A * r1A[2] + e1B * r1B[2]; g1.w = e1A * r1A[3] + e1B * r1B[3];
      S0 += __shfl_xor(S0, 32, 64); S1 += __shfl_xor(S1, 32, 64);
      g0.x += __shfl_xor(g0.x, 32, 64); g0.y += __shfl_xor(g0.y, 32, 64);
      g0.z += __shfl_xor(g0.z, 32, 64); g0.w += __shfl_xor(g0.w, 32, 64);
      g1.x += __shfl_xor(g1.x, 32, 64); g1.y += __shfl_xor(g1.y, 32, 64);
      g1.z += __shfl_xor(g1.z, 32, 64); g1.w += __shfl_xor(g1.w, 32, 64);
      if (half == 0) {
        *(float4*)&wpart[wv][0][4 + h0] = g0;
        *(float4*)&wpart[wv][1][4 + h0] = g1;
        if (hl == 0) { wpart[wv][0][0] = S0; wpart[wv][1][0] = S1; }
      }
      __syncthreads();
      float* ab = accum + ABUF(p & 3, g);
      float* zb = accum + ABUF((p + 1) & 3, g);
      if (tid < 256) {  // block combine -> atomic accumulate at coherence pt
        const int m = tid >> 7, h = tid & 127;
        float gs = 0.f;
        for (int w = 0; w < NW; ++w) gs += wpart[w][m][4 + h];
        unsafeAtomicAdd(&ab[m * 132 + 4 + h], gs);
        if (h == 0) {
          float ss = 0.f;
          for (int w = 0; w < NW; ++w) ss += wpart[w][m][0];
          unsafeAtomicAdd(&ab[m * 132], ss);
        }
      } else if (tid >= 512 && tid < 512 + 17) {  // zero next phase's buffer
        const int idx = c * 17 + (tid - 512);
        if (idx < 272) astore(&zb[idx], 0.f);
      }
      gbar(fl, c, p, tid, lane);
      p++;
      // group read: ONE coherent load per thread (sum already formed)
      if (tid < 256) gfraw[tid] = aload(&ab[(tid >> 7) * 132 + 4 + (tid & 127)]);
      if (tid >= 256 && tid < 258) sS[tid - 256] = aload(&ab[(tid - 256) * 132]);
      __syncthreads();
      {  // merge heads from LDS Wmh, divide folded in: q = (gx @ Wmh)/S
        const int h = tid & 127, part = tid >> 7;
        const int m = part >> 2;
        float acc = 0.f;
        const float* wl = Wmh_lds + (size_t)part * 32 * 128 + h;
        const float* gg = gfraw + part * 32;
#pragma unroll 16
        for (int i = 0; i < 32; ++i) acc += gg[i] * wl[i * 128];
        mpart[part][h] = acc / sS[m];
      }
      __syncthreads();
      if (tid < 128) {
        float acc = 0.f;
        for (int w = 0; w < 8; ++w) acc += mpart[w][tid];
        qcur[tid] = acc;
      }
      __syncthreads();
    }

    // ---- pointer ----
    const float* r2p = proj + (size_t)12 * TPT + ((size_t)g * Nn + start) * Hh + h0;
    const f32x4 rrA = NTL(r2p + o1);   // hoisted + pinned
    const f32x4 rrB = NTL(r2p + o2);
    __builtin_amdgcn_sched_barrier(0);
    {  // qptr = qcur @ Wq2 — 8-way split, seg 16
      const int h = tid & 127, part = tid >> 7;
      float acc = 0.f;
      const float* wp = Wq2 + (size_t)part * 16 * 128 + h;
      const float* qc = qcur + part * 16;
#pragma unroll
      for (int i = 0; i < 16; ++i) acc += qc[i] * wp[(size_t)i * 128];
      mpart[part][h] = acc;
    }
    __syncthreads();
    if (tid < 128) {
      float acc = 0.f;
      for (int w = 0; w < 8; ++w) acc += mpart[w][tid];
      qm[0][tid] = acc;
    }
    __syncthreads();
    {
      const f32x4 q2 = *(const f32x4*)&qm[0][h0];
      const f32x4 vz = *(const f32x4*)&vecl[h0];
      float upA = dot4t(q2, rrA, vz);
      float upB = dot4t(q2, rrB, vz);
      red5_2(upA, upB);
      const float mlA = maskl[jrow], mlB = maskl[j2c];
      const float uA = 10.f * tanh_fast(upA) - 1e8f * mlA;
      const float uB = a2 ? (10.f * tanh_fast(upB) - 1e8f * mlB) : -3.0e38f;
      if (hl == 0) {
        ulocal[jrow] = uA;
        if (a2) ulocal[j2] = uB;
      }
      float Sv = __expf(uA - 10.f) + (a2 ? __expf(uB - 10.f) : 0.f);
      float um = uA; int ui = start + jrow;
      if (a2 && uB > um) { um = uB; ui = start + j2; }
      Sv += __shfl_xor(Sv, 32, 64);
      const float um2 = __shfl_xor(um, 32, 64);
      const int ui2 = __shfl_xor(ui, 32, 64);
      if (um2 > um || (um2 == um && ui2 < ui)) { um = um2; ui = ui2; }
      if (lane == 0) {
        wpart[wv][0][0] = Sv; wpart[wv][0][1] = um;
        wpart[wv][0][2] = __int_as_float(ui);
      }
    }
    __syncthreads();
    float* ab = accum + ABUF(p & 3, g);
    float* zb = accum + ABUF((p + 1) & 3, g);
    if (tid == 0) {  // fused group argmax/logZ: 1 atomicAdd + 1 u64 atomicMax
      float St = 0.f, bm = -3.0e38f; int bi = 0x7fffffff;
      for (int ww = 0; ww < NW; ++ww) {
        St += wpart[ww][0][0];
        const float m2 = wpart[ww][0][1];
        const int i2 = __float_as_int(wpart[ww][0][2]);
        if (m2 > bm || (m2 == bm && i2 < bi)) { bm = m2; bi = i2; }
      }
      unsigned ob = __float_as_uint(bm);
      ob = (ob & 0x80000000u) ? ~ob : (ob | 0x80000000u);  // orderable float
      const unsigned long long key =
          ((unsigned long long)ob << 32) | (0xFFFFFFFFu - (unsigned)bi);
      unsafeAtomicAdd(&ab[0], St);
      atomicMax((unsigned long long*)&ab[264], key);
    } else if (tid >= 512 && tid < 512 + 17) {  // zero next phase's buffer
      const int idx = c * 17 + (tid - 512);
      if (idx < 272) astore(&zb[idx], 0.f);
    }
    gbar(fl, c, p, tid, lane);
    p++;
    if (tid == 0) {  // single coherent RT: St + packed key
      const float St = aload(&ab[0]);
      const unsigned long long key = __hip_atomic_load(
          (const unsigned long long*)&ab[264], __ATOMIC_RELAXED,
          __HIP_MEMORY_SCOPE_AGENT);
      sel_sh = (int)(0xFFFFFFFFu - (unsigned)(key & 0xFFFFFFFFu));
      logZ_sh = 10.f + __logf(St);
    }
    __syncthreads();
    const int sel = sel_sh;
    const float lz = logZ_sh;
    if (tid < 128)  // prefetch selected row for next step's glimpse-1
      qprev[tid] = enc[((size_t)g * Nn + sel) * Hh + tid];
    for (int j = tid; j < cnt; j += TPB)
      out[(size_t)step * (Bb * Nn) + (size_t)g * Nn + start + j] = ulocal[j] - lz;
    if (c == 0 && tid == 0)
      out[(size_t)Ss * Bb * Nn + (size_t)step * Bb + g] = (float)sel;
    if (tid == 0 && sel >= start && sel < start + cnt) maskl[sel - start] = 1.0f;
    __syncthreads();
  }
}

// -------------------------------------------------------------------- launch
extern "C" void kernel_launch(void* const* d_in, const int* in_sizes, int n_in,
                              void* d_out, int out_size, void* d_ws, size_t ws_size,
                              hipStream_t stream) {
  const float* enc     = (const float*)d_in[0];
  const float* mask0   = (const float*)d_in[1];
  const float* Wq1     = (const float*)d_in[2];
  const float* Wref1   = (const float*)d_in[3];
  const float* Vec1    = (const float*)d_in[4];
  const float* Wq3     = (const float*)d_in[5];
  const float* Wref3   = (const float*)d_in[6];
  const float* Vec3    = (const float*)d_in[7];
  const float* Wq4     = (const float*)d_in[8];
  const float* Wref4   = (const float*)d_in[9];
  const float* Vec4    = (const float*)d_in[10];
  const float* Wmh     = (const float*)d_in[11];
  const float* Wq2     = (const float*)d_in[12];
  const float* Wref2   = (const float*)d_in[13];
  const float* Vec2    = (const float*)d_in[14];
  const float* dec_inp = (const float*)d_in[15];
  float* out = (float*)d_out;

  char* ws = (char*)d_ws;
  int* flags      = (int*)ws;                          // 32,768 B
  float* accum    = (float*)(ws + 32768);              // 4*16*272*4 = 69,632 B
  float* partials = (float*)(ws + 102400);             // 540,672 B
  float* proj     = (float*)(ws + 102400 + 540672);    // 13 * 2,048,000 f32

  hipMemsetAsync(ws, 0, 102400, stream);  // zero flags + accum buffers

  dim3 pg(250, 26);
  ptr1_proj_kernel<<<pg, 256, 0, stream>>>(enc, Wref1, Vec1, Wref3, Vec3,
                                           Wref4, Vec4, Wref2, proj);

  void* args[] = {(void*)&enc,  (void*)&mask0, (void*)&Wq1, (void*)&Wq3,
                  (void*)&Wq4,  (void*)&Wmh,   (void*)&Wq2, (void*)&Vec2,
                  (void*)&dec_inp, (void*)&proj, (void*)&partials,
                  (void*)&accum, (void*)&flags, (void*)&out};
  hipLaunchCooperativeKernel((const void*)ptr1_decode_kernel, dim3(256),
                             dim3(1024), args, 0, stream);
}